// Round 8
// baseline (281.692 us; speedup 1.0000x reference)
//
#include <hip/hip_runtime.h>
#include <math.h>

// ---------------------------------------------------------------------------
// GraphSAGE 3-layer forward.
//  - transforms: MFMA bf16 GEMM (16 nodes/wave), yl bf16 + yr fp32+bias
//  - aggregates: sub-wave-per-node register accumulation, degree-balanced via
//    a counting-sort node permutation (R8: waves previously ran to the MAX
//    degree of their 8 node-groups, E[max of 8 Poisson(12)]~18 vs mean 12)
//  - CSR build: atomic-free 2-level bucket sort (R7)
// Assumes N <= 2^17 and ceil(N/512) <= 256.
// ---------------------------------------------------------------------------

typedef __attribute__((ext_vector_type(8))) short short8;
typedef __attribute__((ext_vector_type(4))) float floatx4;

__device__ __forceinline__ unsigned short f2bf(float f) {   // RNE
    unsigned u = __float_as_uint(f);
    u += 0x7fffu + ((u >> 16) & 1u);
    return (unsigned short)(u >> 16);
}
__device__ __forceinline__ float blo(unsigned u) { return __uint_as_float(u << 16); }
__device__ __forceinline__ float bhi(unsigned u) { return __uint_as_float(u & 0xffff0000u); }

// ---------------- CSR build (bucketed, atomic-free at global scope) ---------

__global__ __launch_bounds__(256) void hist_kernel(
        const int* __restrict__ ei, int* __restrict__ bh, int E, int NB, int NBKT) {
    __shared__ int lh[256];
    const int tid = threadIdx.x, blk = blockIdx.x;
    if (tid < NBKT) lh[tid] = 0;
    __syncthreads();
    const int base = blk << 12;
#pragma unroll
    for (int i = 0; i < 16; ++i) {
        const int e = base + (i << 8) + tid;
        if (e < E) atomicAdd(&lh[((unsigned)ei[E + e]) >> 9], 1);
    }
    __syncthreads();
    if (tid < NBKT) bh[tid * NB + blk] = lh[tid];
}

// generic: per-bucket exclusive scan over NB blocks (one wave per bucket)
__global__ __launch_bounds__(256) void bscan_kernel(
        const int* __restrict__ bh, int* __restrict__ offs, int* __restrict__ btot,
        int NB, int NBKT) {
    const int lane = threadIdx.x & 63;
    const int w = blockIdx.x * 4 + (threadIdx.x >> 6);
    if (w >= NBKT) return;
    int running = 0;
    for (int base = 0; base < NB; base += 64) {
        const int j = base + lane;
        const int v = (j < NB) ? bh[w * NB + j] : 0;
        int incl = v;
#pragma unroll
        for (int off = 1; off < 64; off <<= 1) {
            const int t = __shfl_up(incl, off);
            if (lane >= off) incl += t;
        }
        if (j < NB) offs[w * NB + j] = running + incl - v;
        running += __shfl(incl, 63);
    }
    if (lane == 0) btot[w] = running;
}

// generic: exclusive scan over NBKT totals -> base[0..NBKT]
__global__ __launch_bounds__(64) void bucketbase_kernel(
        const int* __restrict__ btot, int* __restrict__ bucket_base, int NBKT) {
    const int lane = threadIdx.x;
    int running = 0;
    for (int base = 0; base < NBKT; base += 64) {
        const int j = base + lane;
        const int v = (j < NBKT) ? btot[j] : 0;
        int incl = v;
#pragma unroll
        for (int off = 1; off < 64; off <<= 1) {
            const int t = __shfl_up(incl, off);
            if (lane >= off) incl += t;
        }
        if (j < NBKT) bucket_base[j] = running + incl - v;
        running += __shfl(incl, 63);
    }
    if (lane == 0) bucket_base[NBKT] = running;
}

__global__ __launch_bounds__(256) void scatter_kernel(
        const int* __restrict__ ei, const int* __restrict__ offs,
        const int* __restrict__ bucket_base, unsigned* __restrict__ ebuf,
        int E, int NB, int NBKT) {
    __shared__ int lcur[256];
    const int tid = threadIdx.x, blk = blockIdx.x;
    if (tid < NBKT) lcur[tid] = bucket_base[tid] + offs[tid * NB + blk];
    __syncthreads();
    const int base = blk << 12;
#pragma unroll
    for (int i = 0; i < 16; ++i) {
        const int e = base + (i << 8) + tid;
        if (e < E) {
            const int s = ei[e];
            const unsigned d = (unsigned)ei[E + e];
            const int p = atomicAdd(&lcur[d >> 9], 1);
            ebuf[p] = ((d & 511u) << 17) | (unsigned)s;
        }
    }
}

__global__ __launch_bounds__(512) void bucket_csr_kernel(
        const unsigned* __restrict__ ebuf, const int* __restrict__ bucket_base,
        int* __restrict__ rowptr, int* __restrict__ deg, int* __restrict__ col,
        int N) {
    __shared__ int ldeg[512];
    __shared__ int buf[512];
    __shared__ int lcur[512];
    const int b = blockIdx.x, tid = threadIdx.x;
    const int segbase = bucket_base[b];
    const int L = bucket_base[b + 1] - segbase;
    ldeg[tid] = 0;
    __syncthreads();
    for (int i = tid; i < L; i += 512) atomicAdd(&ldeg[ebuf[segbase + i] >> 17], 1);
    __syncthreads();
    buf[tid] = ldeg[tid];
    __syncthreads();
    for (int off = 1; off < 512; off <<= 1) {
        const int t = (tid >= off) ? buf[tid - off] : 0;
        __syncthreads();
        buf[tid] += t;
        __syncthreads();
    }
    const int excl = buf[tid] - ldeg[tid];
    const int node = (b << 9) + tid;
    if (node < N) { rowptr[node] = segbase + excl; deg[node] = ldeg[tid]; }
    lcur[tid] = excl;
    __syncthreads();
    for (int i = tid; i < L; i += 512) {
        const unsigned p = ebuf[segbase + i];
        const int pos = atomicAdd(&lcur[p >> 17], 1);
        col[segbase + pos] = (int)(p & 0x1FFFFu);
    }
}

// ---------------- degree-balanced permutation (counting sort by degree) -----
// 512 deg bins (clamped). Per-block LDS hist over 4096 nodes -> dh[d*NDB+blk];
// then bscan/bucketbase reuse; then LDS-cursor scatter into perm.
__global__ __launch_bounds__(512) void deg_hist_kernel(
        const int* __restrict__ deg, int* __restrict__ dh, int N, int NDB) {
    __shared__ int lh[512];
    const int tid = threadIdx.x, blk = blockIdx.x;
    lh[tid] = 0;
    __syncthreads();
    const int base = blk << 12;
#pragma unroll
    for (int i = 0; i < 8; ++i) {
        const int node = base + (i << 9) + tid;
        if (node < N) atomicAdd(&lh[min(deg[node], 511)], 1);
    }
    __syncthreads();
    dh[tid * NDB + blk] = lh[tid];
}

__global__ __launch_bounds__(512) void deg_scatter_kernel(
        const int* __restrict__ deg, const int* __restrict__ doffs,
        const int* __restrict__ degbase, int* __restrict__ perm, int N, int NDB) {
    __shared__ int lcur[512];
    const int tid = threadIdx.x, blk = blockIdx.x;
    lcur[tid] = degbase[tid] + doffs[tid * NDB + blk];
    __syncthreads();
    const int base = blk << 12;
#pragma unroll
    for (int i = 0; i < 8; ++i) {
        const int node = base + (i << 9) + tid;
        if (node < N) {
            const int pos = atomicAdd(&lcur[min(deg[node], 511)], 1);
            perm[pos] = node;
        }
    }
}

// ---------------- MFMA transform: y_l = A@Wl (bf16), y_r = A@Wr + b (fp32) ---
template <int K, int F_OUT, int PAD, bool AFP32>
__global__ __launch_bounds__(256) void transform_kernel(
        const void* __restrict__ Ain, const float* __restrict__ Wl,
        const float* __restrict__ Wr, const float* __restrict__ b,
        unsigned short* __restrict__ yl, float* __restrict__ yr, int n) {
    constexpr int KSTEP = K / 32;
    constexpr int NT = PAD / 16;
    const int lane = threadIdx.x & 63;
    const int wid = (blockIdx.x * blockDim.x + threadIdx.x) >> 6;
    const int ntiles = (n + 15) >> 4;
    if (wid >= ntiles) return;
    const int nl = lane & 15, q = lane >> 4;

    short8 Bl[NT][KSTEP], Br[NT][KSTEP];
    float biasv[NT];
#pragma unroll
    for (int t = 0; t < NT; ++t) {
        const int ncol = t * 16 + nl;
        biasv[t] = (ncol < F_OUT) ? b[ncol] : 0.f;
#pragma unroll
        for (int ks = 0; ks < KSTEP; ++ks) {
#pragma unroll
            for (int j = 0; j < 8; ++j) {
                const int k = ks * 32 + q * 8 + j;
                Bl[t][ks][j] = (ncol < F_OUT) ? (short)f2bf(Wl[k * F_OUT + ncol]) : (short)0;
                Br[t][ks][j] = (ncol < F_OUT) ? (short)f2bf(Wr[k * F_OUT + ncol]) : (short)0;
            }
        }
    }

    const int m0 = wid * 16;
    int m = m0 + nl; if (m >= n) m = n - 1;

    short8 a[KSTEP];
#pragma unroll
    for (int ks = 0; ks < KSTEP; ++ks) {
        if (AFP32) {
            const float* p = (const float*)Ain + (size_t)m * K + ks * 32 + q * 8;
#pragma unroll
            for (int j = 0; j < 8; ++j) a[ks][j] = (short)f2bf(p[j]);
        } else {
            union { uint4 u; short8 s; } cvt;
            cvt.u = *(const uint4*)((const unsigned short*)Ain + (size_t)m * K + ks * 32 + q * 8);
            a[ks] = cvt.s;
        }
    }

    floatx4 accl[NT], accr[NT];
#pragma unroll
    for (int t = 0; t < NT; ++t) { accl[t] = {0.f,0.f,0.f,0.f}; accr[t] = {0.f,0.f,0.f,0.f}; }
#pragma unroll
    for (int ks = 0; ks < KSTEP; ++ks) {
#pragma unroll
        for (int t = 0; t < NT; ++t) {
            accl[t] = __builtin_amdgcn_mfma_f32_16x16x32_bf16(a[ks], Bl[t][ks], accl[t], 0, 0, 0);
            accr[t] = __builtin_amdgcn_mfma_f32_16x16x32_bf16(a[ks], Br[t][ks], accr[t], 0, 0, 0);
        }
    }

#pragma unroll
    for (int t = 0; t < NT; ++t) {
        const int ncol = t * 16 + nl;
#pragma unroll
        for (int r = 0; r < 4; ++r) {
            const int node = m0 + q * 4 + r;
            if (node < n) {
                yl[(size_t)node * PAD + ncol] = f2bf(accl[t][r]);
                yr[(size_t)node * PAD + ncol] = accr[t][r] + biasv[t];
            }
        }
    }
}

// ---------------- aggregate: h = act(norm(mean_gather(yl) + yr)) ------------
// Nodes taken through degree-balanced perm; unroll-4 gather.
template <int F, int ACT>
__global__ __launch_bounds__(256) void agg_kernel(
        const unsigned short* __restrict__ yl, const float* __restrict__ yr,
        const int* __restrict__ rowptr, const int* __restrict__ degv,
        const int* __restrict__ col, const int* __restrict__ perm,
        unsigned short* __restrict__ hout, float* __restrict__ fout, int n) {
    constexpr int G = F / 8;
    constexpr int NPW = 64 / G;
    const int lane = threadIdx.x & 63;
    const int wid = (blockIdx.x * blockDim.x + threadIdx.x) >> 6;
    const int g = lane / G, c = lane % G;
    const int idx = wid * NPW + g;
    if (idx >= n) return;
    const int node = perm[idx];

    const int beg = rowptr[node];
    const int dg  = degv[node];
    const unsigned short* base = yl + c * 8;

    float a0=0.f,a1=0.f,a2=0.f,a3=0.f,a4=0.f,a5=0.f,a6=0.f,a7=0.f;
    int i = 0;
    for (; i + 4 <= dg; i += 4) {                   // 4 rows in flight
        const int n0 = col[beg + i], n1 = col[beg + i + 1];
        const int n2 = col[beg + i + 2], n3 = col[beg + i + 3];
        const uint4 t0 = *(const uint4*)(base + (size_t)n0 * F);
        const uint4 t1 = *(const uint4*)(base + (size_t)n1 * F);
        const uint4 t2 = *(const uint4*)(base + (size_t)n2 * F);
        const uint4 t3 = *(const uint4*)(base + (size_t)n3 * F);
        a0 += blo(t0.x) + blo(t1.x) + blo(t2.x) + blo(t3.x);
        a1 += bhi(t0.x) + bhi(t1.x) + bhi(t2.x) + bhi(t3.x);
        a2 += blo(t0.y) + blo(t1.y) + blo(t2.y) + blo(t3.y);
        a3 += bhi(t0.y) + bhi(t1.y) + bhi(t2.y) + bhi(t3.y);
        a4 += blo(t0.z) + blo(t1.z) + blo(t2.z) + blo(t3.z);
        a5 += bhi(t0.z) + bhi(t1.z) + bhi(t2.z) + bhi(t3.z);
        a6 += blo(t0.w) + blo(t1.w) + blo(t2.w) + blo(t3.w);
        a7 += bhi(t0.w) + bhi(t1.w) + bhi(t2.w) + bhi(t3.w);
    }
    for (; i < dg; ++i) {
        const uint4 t0 = *(const uint4*)(base + (size_t)col[beg + i] * F);
        a0 += blo(t0.x); a1 += bhi(t0.x); a2 += blo(t0.y); a3 += bhi(t0.y);
        a4 += blo(t0.z); a5 += bhi(t0.z); a6 += blo(t0.w); a7 += bhi(t0.w);
    }
    const float inv = (dg > 0) ? 1.f / (float)dg : 0.f;

    const floatx4* yp = (const floatx4*)(yr + (size_t)node * F + c * 8);
    const floatx4 r0 = yp[0], r1 = yp[1];
    float o[8];
    o[0] = a0*inv + r0.x; o[1] = a1*inv + r0.y; o[2] = a2*inv + r0.z; o[3] = a3*inv + r0.w;
    o[4] = a4*inv + r1.x; o[5] = a5*inv + r1.y; o[6] = a6*inv + r1.z; o[7] = a7*inv + r1.w;

    float ss = 0.f;
#pragma unroll
    for (int j = 0; j < 8; ++j) ss += o[j] * o[j];
#pragma unroll
    for (int off = 1; off < G; off <<= 1) ss += __shfl_xor(ss, off);
    const float scale = 1.f / fmaxf(sqrtf(ss), 1e-12f);

    if (ACT == 1) {
        uint4 u;
        float h[8];
#pragma unroll
        for (int j = 0; j < 8; ++j) h[j] = fmaxf(o[j] * scale, 0.f);
        u.x = (unsigned)f2bf(h[0]) | ((unsigned)f2bf(h[1]) << 16);
        u.y = (unsigned)f2bf(h[2]) | ((unsigned)f2bf(h[3]) << 16);
        u.z = (unsigned)f2bf(h[4]) | ((unsigned)f2bf(h[5]) << 16);
        u.w = (unsigned)f2bf(h[6]) | ((unsigned)f2bf(h[7]) << 16);
        *(uint4*)(hout + (size_t)node * F + c * 8) = u;
    } else {
#pragma unroll
        for (int j = 0; j < 8; ++j) o[j] *= scale;
        const int cbase = c * 8;
        float m = -INFINITY;
#pragma unroll
        for (int j = 0; j < 8; ++j) if (cbase + j < 10) m = fmaxf(m, o[j]);
        m = fmaxf(m, __shfl_xor(m, 1));
        float s = 0.f;
#pragma unroll
        for (int j = 0; j < 8; ++j) if (cbase + j < 10) s += __expf(o[j] - m);
        s += __shfl_xor(s, 1);
        const float ls = logf(s);
#pragma unroll
        for (int j = 0; j < 8; ++j)
            if (cbase + j < 10) fout[(size_t)node * 10 + cbase + j] = o[j] - m - ls;
    }
}

extern "C" void kernel_launch(void* const* d_in, const int* in_sizes, int n_in,
                              void* d_out, int out_size, void* d_ws, size_t ws_size,
                              hipStream_t stream) {
    const float* x   = (const float*)d_in[0];
    const int*   ei  = (const int*)d_in[1];     // int64 in ref -> int32 on device
    const float* W1l = (const float*)d_in[2];
    const float* W1r = (const float*)d_in[3];
    const float* b1  = (const float*)d_in[4];
    const float* W2l = (const float*)d_in[5];
    const float* W2r = (const float*)d_in[6];
    const float* b2  = (const float*)d_in[7];
    const float* W3l = (const float*)d_in[8];
    const float* W3r = (const float*)d_in[9];
    const float* b3  = (const float*)d_in[10];
    float*       out = (float*)d_out;

    const int N = in_sizes[0] / 64;
    const int E = in_sizes[1] / 2;
    const int NBKT = (N + 511) >> 9;     // dst buckets of 512 nodes (<=256)
    const int NB   = (E + 4095) >> 12;   // 4096 edges per hist/scatter block
    const int NDB  = (N + 4095) >> 12;   // 4096 nodes per deg-hist block

    auto align16 = [](size_t v) { return (v + 15) & ~(size_t)15; };
    char* ws = (char*)d_ws;
    size_t off = 0;
    int* rowptr  = (int*)(ws + off); off = align16(off + (size_t)N * 4);
    int* deg     = (int*)(ws + off); off = align16(off + (size_t)N * 4);
    int* perm    = (int*)(ws + off); off = align16(off + (size_t)N * 4);
    int* colidx  = (int*)(ws + off); off = align16(off + (size_t)E * 4);
    unsigned* ebuf = (unsigned*)(ws + off); off = align16(off + (size_t)E * 4);
    int* bh      = (int*)(ws + off); off = align16(off + (size_t)NBKT * NB * 4);
    int* offsb   = (int*)(ws + off); off = align16(off + (size_t)NBKT * NB * 4);
    int* btot    = (int*)(ws + off); off = align16(off + (size_t)NBKT * 4);
    int* bbase   = (int*)(ws + off); off = align16(off + (size_t)(NBKT + 1) * 4);
    int* dh      = (int*)(ws + off); off = align16(off + (size_t)512 * NDB * 4);
    int* doffs   = (int*)(ws + off); off = align16(off + (size_t)512 * NDB * 4);
    int* dtot    = (int*)(ws + off); off = align16(off + (size_t)512 * 4);
    int* degbase = (int*)(ws + off); off = align16(off + (size_t)513 * 4);
    unsigned short* y1l = (unsigned short*)(ws + off); off = align16(off + (size_t)N * 64 * 2);
    float*          y1r = (float*)(ws + off);          off = align16(off + (size_t)N * 64 * 4);
    unsigned short* h1  = (unsigned short*)(ws + off); off = align16(off + (size_t)N * 64 * 2);
    unsigned short* y2l = (unsigned short*)(ws + off); off = align16(off + (size_t)N * 32 * 2);
    float*          y2r = (float*)(ws + off);          off = align16(off + (size_t)N * 32 * 4);
    unsigned short* h2  = (unsigned short*)(ws + off); off = align16(off + (size_t)N * 32 * 2);
    unsigned short* y3l = (unsigned short*)(ws + off); off = align16(off + (size_t)N * 16 * 2);
    float*          y3r = (float*)(ws + off);          off = align16(off + (size_t)N * 16 * 4);
    (void)ws_size; (void)n_in; (void)out_size;

    // ---- CSR build (atomic-free bucket sort)
    hist_kernel<<<NB, 256, 0, stream>>>(ei, bh, E, NB, NBKT);
    bscan_kernel<<<(NBKT + 3) / 4, 256, 0, stream>>>(bh, offsb, btot, NB, NBKT);
    bucketbase_kernel<<<1, 64, 0, stream>>>(btot, bbase, NBKT);
    scatter_kernel<<<NB, 256, 0, stream>>>(ei, offsb, bbase, ebuf, E, NB, NBKT);
    bucket_csr_kernel<<<NBKT, 512, 0, stream>>>(ebuf, bbase, rowptr, deg, colidx, N);

    // ---- degree-balanced permutation
    deg_hist_kernel<<<NDB, 512, 0, stream>>>(deg, dh, N, NDB);
    bscan_kernel<<<(512 + 3) / 4, 256, 0, stream>>>(dh, doffs, dtot, NDB, 512);
    bucketbase_kernel<<<1, 64, 0, stream>>>(dtot, degbase, 512);
    deg_scatter_kernel<<<NDB, 512, 0, stream>>>(deg, doffs, degbase, perm, N, NDB);

    const int ntiles = (N + 15) / 16;                  // MFMA node tiles
    const int tblocks = (ntiles * 64 + 255) / 256;     // 4 waves/block

    // layer 1
    transform_kernel<64, 64, 64, true><<<tblocks, 256, 0, stream>>>(x, W1l, W1r, b1, y1l, y1r, N);
    agg_kernel<64, 1><<<(N + 31) / 32, 256, 0, stream>>>(y1l, y1r, rowptr, deg, colidx, perm, h1, nullptr, N);
    // layer 2
    transform_kernel<64, 32, 32, false><<<tblocks, 256, 0, stream>>>(h1, W2l, W2r, b2, y2l, y2r, N);
    agg_kernel<32, 1><<<(N + 63) / 64, 256, 0, stream>>>(y2l, y2r, rowptr, deg, colidx, perm, h2, nullptr, N);
    // layer 3
    transform_kernel<32, 10, 16, false><<<tblocks, 256, 0, stream>>>(h2, W3l, W3r, b3, y3l, y3r, N);
    agg_kernel<16, 2><<<(N + 127) / 128, 256, 0, stream>>>(y3l, y3r, rowptr, deg, colidx, perm, nullptr, out, N);
}

// Round 10
// 242.462 us; speedup vs baseline: 1.1618x; 1.1618x over previous
//
#include <hip/hip_runtime.h>
#include <math.h>

// ---------------------------------------------------------------------------
// GraphSAGE 3-layer forward.
//  - transforms: MFMA bf16 GEMM (16 nodes/wave), yl bf16 + yr fp32+bias
//  - aggregates: sub-wave-per-node register accumulation, CONSECUTIVE node
//    assignment (R8: degree-permutation cost +24MB FETCH from lost locality),
//    unroll-4 gather for 4 rows in flight per group.
//  - CSR build: atomic-free 2-level bucket sort (R7).
//  - R10: defensive index clamps (R9 aborted; audit found no reachable OOB —
//    suspected transient fault — clamps make any corruption non-faulting).
// Assumes N <= 2^17 and ceil(N/512) <= 256.
// ---------------------------------------------------------------------------

typedef __attribute__((ext_vector_type(8))) short short8;
typedef __attribute__((ext_vector_type(4))) float floatx4;

__device__ __forceinline__ unsigned short f2bf(float f) {   // RNE
    unsigned u = __float_as_uint(f);
    u += 0x7fffu + ((u >> 16) & 1u);
    return (unsigned short)(u >> 16);
}
__device__ __forceinline__ float blo(unsigned u) { return __uint_as_float(u << 16); }
__device__ __forceinline__ float bhi(unsigned u) { return __uint_as_float(u & 0xffff0000u); }

// ---------------- CSR build (bucketed, atomic-free at global scope) ---------

__global__ __launch_bounds__(256) void hist_kernel(
        const int* __restrict__ ei, int* __restrict__ bh, int E, int NB, int NBKT) {
    __shared__ int lh[256];
    const int tid = threadIdx.x, blk = blockIdx.x;
    lh[tid] = 0;
    __syncthreads();
    const int base = blk << 12;
#pragma unroll
    for (int i = 0; i < 16; ++i) {
        const int e = base + (i << 8) + tid;
        if (e < E) atomicAdd(&lh[min((int)(((unsigned)ei[E + e]) >> 9), NBKT - 1)], 1);
    }
    __syncthreads();
    if (tid < NBKT) bh[tid * NB + blk] = lh[tid];
}

__global__ __launch_bounds__(256) void bscan_kernel(
        const int* __restrict__ bh, int* __restrict__ offs, int* __restrict__ btot,
        int NB, int NBKT) {
    const int lane = threadIdx.x & 63;
    const int w = blockIdx.x * 4 + (threadIdx.x >> 6);
    if (w >= NBKT) return;
    int running = 0;
    for (int base = 0; base < NB; base += 64) {
        const int j = base + lane;
        const int v = (j < NB) ? bh[w * NB + j] : 0;
        int incl = v;
#pragma unroll
        for (int off = 1; off < 64; off <<= 1) {
            const int t = __shfl_up(incl, off);
            if (lane >= off) incl += t;
        }
        if (j < NB) offs[w * NB + j] = running + incl - v;
        running += __shfl(incl, 63);
    }
    if (lane == 0) btot[w] = running;
}

__global__ __launch_bounds__(64) void bucketbase_kernel(
        const int* __restrict__ btot, int* __restrict__ bucket_base, int NBKT) {
    const int lane = threadIdx.x;
    int running = 0;
    for (int base = 0; base < NBKT; base += 64) {
        const int j = base + lane;
        const int v = (j < NBKT) ? btot[j] : 0;
        int incl = v;
#pragma unroll
        for (int off = 1; off < 64; off <<= 1) {
            const int t = __shfl_up(incl, off);
            if (lane >= off) incl += t;
        }
        if (j < NBKT) bucket_base[j] = running + incl - v;
        running += __shfl(incl, 63);
    }
    if (lane == 0) bucket_base[NBKT] = running;
}

__global__ __launch_bounds__(256) void scatter_kernel(
        const int* __restrict__ ei, const int* __restrict__ offs,
        const int* __restrict__ bucket_base, unsigned* __restrict__ ebuf,
        int E, int NB, int NBKT) {
    __shared__ int lcur[256];
    const int tid = threadIdx.x, blk = blockIdx.x;
    if (tid < NBKT) lcur[tid] = bucket_base[tid] + offs[tid * NB + blk];
    __syncthreads();
    const int base = blk << 12;
#pragma unroll
    for (int i = 0; i < 16; ++i) {
        const int e = base + (i << 8) + tid;
        if (e < E) {
            const int s = ei[e];
            const unsigned d = (unsigned)ei[E + e];
            int p = atomicAdd(&lcur[min((int)(d >> 9), NBKT - 1)], 1);
            p = min(p, E - 1);                       // defensive
            ebuf[p] = ((d & 511u) << 17) | (unsigned)s;
        }
    }
}

__global__ __launch_bounds__(512) void bucket_csr_kernel(
        const unsigned* __restrict__ ebuf, const int* __restrict__ bucket_base,
        int* __restrict__ rowptr, int* __restrict__ deg, int* __restrict__ col,
        int N, int E) {
    __shared__ int ldeg[512];
    __shared__ int buf[512];
    __shared__ int lcur[512];
    const int b = blockIdx.x, tid = threadIdx.x;
    const int segbase = bucket_base[b];
    const int L = bucket_base[b + 1] - segbase;
    ldeg[tid] = 0;
    __syncthreads();
    for (int i = tid; i < L; i += 512) atomicAdd(&ldeg[ebuf[segbase + i] >> 17], 1);
    __syncthreads();
    buf[tid] = ldeg[tid];
    __syncthreads();
    for (int off = 1; off < 512; off <<= 1) {
        const int t = (tid >= off) ? buf[tid - off] : 0;
        __syncthreads();
        buf[tid] += t;
        __syncthreads();
    }
    const int excl = buf[tid] - ldeg[tid];
    const int node = (b << 9) + tid;
    if (node < N) { rowptr[node] = segbase + excl; deg[node] = ldeg[tid]; }
    lcur[tid] = excl;
    __syncthreads();
    for (int i = tid; i < L; i += 512) {
        const unsigned p = ebuf[segbase + i];
        int pos = atomicAdd(&lcur[p >> 17], 1);
        pos = min(segbase + pos, E - 1);             // defensive
        col[pos] = (int)(p & 0x1FFFFu);
    }
}

// ---------------- MFMA transform: y_l = A@Wl (bf16), y_r = A@Wr + b (fp32) ---
template <int K, int F_OUT, int PAD, bool AFP32>
__global__ __launch_bounds__(256) void transform_kernel(
        const void* __restrict__ Ain, const float* __restrict__ Wl,
        const float* __restrict__ Wr, const float* __restrict__ b,
        unsigned short* __restrict__ yl, float* __restrict__ yr, int n) {
    constexpr int KSTEP = K / 32;
    constexpr int NT = PAD / 16;
    const int lane = threadIdx.x & 63;
    const int wid = (blockIdx.x * blockDim.x + threadIdx.x) >> 6;
    const int ntiles = (n + 15) >> 4;
    if (wid >= ntiles) return;
    const int nl = lane & 15, q = lane >> 4;

    short8 Bl[NT][KSTEP], Br[NT][KSTEP];
    float biasv[NT];
#pragma unroll
    for (int t = 0; t < NT; ++t) {
        const int ncol = t * 16 + nl;
        biasv[t] = (ncol < F_OUT) ? b[ncol] : 0.f;
#pragma unroll
        for (int ks = 0; ks < KSTEP; ++ks) {
#pragma unroll
            for (int j = 0; j < 8; ++j) {
                const int k = ks * 32 + q * 8 + j;
                Bl[t][ks][j] = (ncol < F_OUT) ? (short)f2bf(Wl[k * F_OUT + ncol]) : (short)0;
                Br[t][ks][j] = (ncol < F_OUT) ? (short)f2bf(Wr[k * F_OUT + ncol]) : (short)0;
            }
        }
    }

    const int m0 = wid * 16;
    int m = m0 + nl; if (m >= n) m = n - 1;

    short8 a[KSTEP];
#pragma unroll
    for (int ks = 0; ks < KSTEP; ++ks) {
        if (AFP32) {
            const float* p = (const float*)Ain + (size_t)m * K + ks * 32 + q * 8;
#pragma unroll
            for (int j = 0; j < 8; ++j) a[ks][j] = (short)f2bf(p[j]);
        } else {
            union { uint4 u; short8 s; } cvt;
            cvt.u = *(const uint4*)((const unsigned short*)Ain + (size_t)m * K + ks * 32 + q * 8);
            a[ks] = cvt.s;
        }
    }

    floatx4 accl[NT], accr[NT];
#pragma unroll
    for (int t = 0; t < NT; ++t) { accl[t] = {0.f,0.f,0.f,0.f}; accr[t] = {0.f,0.f,0.f,0.f}; }
#pragma unroll
    for (int ks = 0; ks < KSTEP; ++ks) {
#pragma unroll
        for (int t = 0; t < NT; ++t) {
            accl[t] = __builtin_amdgcn_mfma_f32_16x16x32_bf16(a[ks], Bl[t][ks], accl[t], 0, 0, 0);
            accr[t] = __builtin_amdgcn_mfma_f32_16x16x32_bf16(a[ks], Br[t][ks], accr[t], 0, 0, 0);
        }
    }

#pragma unroll
    for (int t = 0; t < NT; ++t) {
        const int ncol = t * 16 + nl;
#pragma unroll
        for (int r = 0; r < 4; ++r) {
            const int node = m0 + q * 4 + r;
            if (node < n) {
                yl[(size_t)node * PAD + ncol] = f2bf(accl[t][r]);
                yr[(size_t)node * PAD + ncol] = accr[t][r] + biasv[t];
            }
        }
    }
}

// ---------------- aggregate: h = act(norm(mean_gather(yl) + yr)) ------------
// Consecutive nodes per wave (locality); unroll-4 gather (4 rows in flight).
template <int F, int ACT>
__global__ __launch_bounds__(256) void agg_kernel(
        const unsigned short* __restrict__ yl, const float* __restrict__ yr,
        const int* __restrict__ rowptr, const int* __restrict__ degv,
        const int* __restrict__ col,
        unsigned short* __restrict__ hout, float* __restrict__ fout, int n) {
    constexpr int G = F / 8;
    constexpr int NPW = 64 / G;
    const int lane = threadIdx.x & 63;
    const int wid = (blockIdx.x * blockDim.x + threadIdx.x) >> 6;
    const int g = lane / G, c = lane % G;
    const int node = wid * NPW + g;
    if (node >= n) return;

    const int beg = rowptr[node];
    const int dg  = degv[node];
    const int nmax = n - 1;
    const unsigned short* base = yl + c * 8;

    float a0=0.f,a1=0.f,a2=0.f,a3=0.f,a4=0.f,a5=0.f,a6=0.f,a7=0.f;
    int i = 0;
    for (; i + 4 <= dg; i += 4) {                   // 4 rows in flight
        const int n0 = min(col[beg + i],     nmax);
        const int n1 = min(col[beg + i + 1], nmax);
        const int n2 = min(col[beg + i + 2], nmax);
        const int n3 = min(col[beg + i + 3], nmax);
        const uint4 t0 = *(const uint4*)(base + (size_t)n0 * F);
        const uint4 t1 = *(const uint4*)(base + (size_t)n1 * F);
        const uint4 t2 = *(const uint4*)(base + (size_t)n2 * F);
        const uint4 t3 = *(const uint4*)(base + (size_t)n3 * F);
        a0 += blo(t0.x) + blo(t1.x) + blo(t2.x) + blo(t3.x);
        a1 += bhi(t0.x) + bhi(t1.x) + bhi(t2.x) + bhi(t3.x);
        a2 += blo(t0.y) + blo(t1.y) + blo(t2.y) + blo(t3.y);
        a3 += bhi(t0.y) + bhi(t1.y) + bhi(t2.y) + bhi(t3.y);
        a4 += blo(t0.z) + blo(t1.z) + blo(t2.z) + blo(t3.z);
        a5 += bhi(t0.z) + bhi(t1.z) + bhi(t2.z) + bhi(t3.z);
        a6 += blo(t0.w) + blo(t1.w) + blo(t2.w) + blo(t3.w);
        a7 += bhi(t0.w) + bhi(t1.w) + bhi(t2.w) + bhi(t3.w);
    }
    for (; i < dg; ++i) {
        const int n0 = min(col[beg + i], nmax);
        const uint4 t0 = *(const uint4*)(base + (size_t)n0 * F);
        a0 += blo(t0.x); a1 += bhi(t0.x); a2 += blo(t0.y); a3 += bhi(t0.y);
        a4 += blo(t0.z); a5 += bhi(t0.z); a6 += blo(t0.w); a7 += bhi(t0.w);
    }
    const float inv = (dg > 0) ? 1.f / (float)dg : 0.f;

    const floatx4* yp = (const floatx4*)(yr + (size_t)node * F + c * 8);
    const floatx4 r0 = yp[0], r1 = yp[1];
    float o[8];
    o[0] = a0*inv + r0.x; o[1] = a1*inv + r0.y; o[2] = a2*inv + r0.z; o[3] = a3*inv + r0.w;
    o[4] = a4*inv + r1.x; o[5] = a5*inv + r1.y; o[6] = a6*inv + r1.z; o[7] = a7*inv + r1.w;

    float ss = 0.f;
#pragma unroll
    for (int j = 0; j < 8; ++j) ss += o[j] * o[j];
#pragma unroll
    for (int off = 1; off < G; off <<= 1) ss += __shfl_xor(ss, off);
    const float scale = 1.f / fmaxf(sqrtf(ss), 1e-12f);

    if (ACT == 1) {
        uint4 u;
        float h[8];
#pragma unroll
        for (int j = 0; j < 8; ++j) h[j] = fmaxf(o[j] * scale, 0.f);
        u.x = (unsigned)f2bf(h[0]) | ((unsigned)f2bf(h[1]) << 16);
        u.y = (unsigned)f2bf(h[2]) | ((unsigned)f2bf(h[3]) << 16);
        u.z = (unsigned)f2bf(h[4]) | ((unsigned)f2bf(h[5]) << 16);
        u.w = (unsigned)f2bf(h[6]) | ((unsigned)f2bf(h[7]) << 16);
        *(uint4*)(hout + (size_t)node * F + c * 8) = u;
    } else {
#pragma unroll
        for (int j = 0; j < 8; ++j) o[j] *= scale;
        const int cbase = c * 8;
        float m = -INFINITY;
#pragma unroll
        for (int j = 0; j < 8; ++j) if (cbase + j < 10) m = fmaxf(m, o[j]);
        m = fmaxf(m, __shfl_xor(m, 1));
        float s = 0.f;
#pragma unroll
        for (int j = 0; j < 8; ++j) if (cbase + j < 10) s += __expf(o[j] - m);
        s += __shfl_xor(s, 1);
        const float ls = logf(s);
#pragma unroll
        for (int j = 0; j < 8; ++j)
            if (cbase + j < 10) fout[(size_t)node * 10 + cbase + j] = o[j] - m - ls;
    }
}

extern "C" void kernel_launch(void* const* d_in, const int* in_sizes, int n_in,
                              void* d_out, int out_size, void* d_ws, size_t ws_size,
                              hipStream_t stream) {
    const float* x   = (const float*)d_in[0];
    const int*   ei  = (const int*)d_in[1];     // int64 in ref -> int32 on device
    const float* W1l = (const float*)d_in[2];
    const float* W1r = (const float*)d_in[3];
    const float* b1  = (const float*)d_in[4];
    const float* W2l = (const float*)d_in[5];
    const float* W2r = (const float*)d_in[6];
    const float* b2  = (const float*)d_in[7];
    const float* W3l = (const float*)d_in[8];
    const float* W3r = (const float*)d_in[9];
    const float* b3  = (const float*)d_in[10];
    float*       out = (float*)d_out;

    const int N = in_sizes[0] / 64;
    const int E = in_sizes[1] / 2;
    const int NBKT = (N + 511) >> 9;     // dst buckets of 512 nodes (<=256)
    const int NB   = (E + 4095) >> 12;   // 4096 edges per hist/scatter block

    auto align16 = [](size_t v) { return (v + 15) & ~(size_t)15; };
    char* ws = (char*)d_ws;
    size_t off = 0;
    int* rowptr  = (int*)(ws + off); off = align16(off + (size_t)N * 4);
    int* deg     = (int*)(ws + off); off = align16(off + (size_t)N * 4);
    int* colidx  = (int*)(ws + off); off = align16(off + (size_t)E * 4);
    unsigned* ebuf = (unsigned*)(ws + off); off = align16(off + (size_t)E * 4);
    int* bh      = (int*)(ws + off); off = align16(off + (size_t)NBKT * NB * 4);
    int* offsb   = (int*)(ws + off); off = align16(off + (size_t)NBKT * NB * 4);
    int* btot    = (int*)(ws + off); off = align16(off + (size_t)NBKT * 4);
    int* bbase   = (int*)(ws + off); off = align16(off + (size_t)(NBKT + 1) * 4);
    unsigned short* y1l = (unsigned short*)(ws + off); off = align16(off + (size_t)N * 64 * 2);
    float*          y1r = (float*)(ws + off);          off = align16(off + (size_t)N * 64 * 4);
    unsigned short* h1  = (unsigned short*)(ws + off); off = align16(off + (size_t)N * 64 * 2);
    unsigned short* y2l = (unsigned short*)(ws + off); off = align16(off + (size_t)N * 32 * 2);
    float*          y2r = (float*)(ws + off);          off = align16(off + (size_t)N * 32 * 4);
    unsigned short* h2  = (unsigned short*)(ws + off); off = align16(off + (size_t)N * 32 * 2);
    unsigned short* y3l = (unsigned short*)(ws + off); off = align16(off + (size_t)N * 16 * 2);
    float*          y3r = (float*)(ws + off);          off = align16(off + (size_t)N * 16 * 4);
    (void)ws_size; (void)n_in; (void)out_size;

    // ---- CSR build (atomic-free bucket sort)
    hist_kernel<<<NB, 256, 0, stream>>>(ei, bh, E, NB, NBKT);
    bscan_kernel<<<(NBKT + 3) / 4, 256, 0, stream>>>(bh, offsb, btot, NB, NBKT);
    bucketbase_kernel<<<1, 64, 0, stream>>>(btot, bbase, NBKT);
    scatter_kernel<<<NB, 256, 0, stream>>>(ei, offsb, bbase, ebuf, E, NB, NBKT);
    bucket_csr_kernel<<<NBKT, 512, 0, stream>>>(ebuf, bbase, rowptr, deg, colidx, N, E);

    const int ntiles = (N + 15) / 16;                  // MFMA node tiles
    const int tblocks = (ntiles * 64 + 255) / 256;     // 4 waves/block

    // layer 1
    transform_kernel<64, 64, 64, true><<<tblocks, 256, 0, stream>>>(x, W1l, W1r, b1, y1l, y1r, N);
    agg_kernel<64, 1><<<(N + 31) / 32, 256, 0, stream>>>(y1l, y1r, rowptr, deg, colidx, h1, nullptr, N);
    // layer 2
    transform_kernel<64, 32, 32, false><<<tblocks, 256, 0, stream>>>(h1, W2l, W2r, b2, y2l, y2r, N);
    agg_kernel<32, 1><<<(N + 63) / 64, 256, 0, stream>>>(y2l, y2r, rowptr, deg, colidx, h2, nullptr, N);
    // layer 3
    transform_kernel<32, 10, 16, false><<<tblocks, 256, 0, stream>>>(h2, W3l, W3r, b3, y3l, y3r, N);
    agg_kernel<16, 2><<<(N + 127) / 128, 256, 0, stream>>>(y3l, y3r, rowptr, deg, colidx, nullptr, out, N);
}

// Round 11
// 222.145 us; speedup vs baseline: 1.2681x; 1.0915x over previous
//
#include <hip/hip_runtime.h>
#include <math.h>

// ---------------------------------------------------------------------------
// GraphSAGE 3-layer forward.
//  - transforms: MFMA bf16 GEMM (16 nodes/wave); layer-1 gather payload y1l
//    stored FP8 e4m3 (R11: random-gather working set 12.8->6.4MB drops below
//    per-XCD 4MB L2 wall -> hit rate up + bytes halved; HW cvt_pk decode),
//    yr residuals bf16 (streamed once, coalesced).
//  - aggregates: sub-wave-per-node register accumulation, consecutive nodes,
//    unroll-4 (R10: concurrency beyond this is NOT the limiter - ~3.4TB/s
//    random-gather ceiling; fewer/hotter bytes is the lever).
//  - CSR build: atomic-free 2-level bucket sort (R7) + defensive clamps (R10).
// Assumes N <= 2^17 and ceil(N/512) <= 256.
// ---------------------------------------------------------------------------

typedef __attribute__((ext_vector_type(8))) short short8;
typedef __attribute__((ext_vector_type(4))) float floatx4;
typedef __attribute__((ext_vector_type(2))) float floatx2;

__device__ __forceinline__ unsigned short f2bf(float f) {   // RNE
    unsigned u = __float_as_uint(f);
    u += 0x7fffu + ((u >> 16) & 1u);
    return (unsigned short)(u >> 16);
}
__device__ __forceinline__ float blo(unsigned u) { return __uint_as_float(u << 16); }
__device__ __forceinline__ float bhi(unsigned u) { return __uint_as_float(u & 0xffff0000u); }
__device__ __forceinline__ unsigned char f2fp8(float f) {   // e4m3fn via HW
    return (unsigned char)(__builtin_amdgcn_cvt_pk_fp8_f32(f, f, 0, false) & 0xFF);
}

// ---------------- CSR build (bucketed, atomic-free at global scope) ---------

__global__ __launch_bounds__(256) void hist_kernel(
        const int* __restrict__ ei, int* __restrict__ bh, int E, int NB, int NBKT) {
    __shared__ int lh[256];
    const int tid = threadIdx.x, blk = blockIdx.x;
    lh[tid] = 0;
    __syncthreads();
    const int base = blk << 12;
#pragma unroll
    for (int i = 0; i < 16; ++i) {
        const int e = base + (i << 8) + tid;
        if (e < E) atomicAdd(&lh[min((int)(((unsigned)ei[E + e]) >> 9), NBKT - 1)], 1);
    }
    __syncthreads();
    if (tid < NBKT) bh[tid * NB + blk] = lh[tid];
}

__global__ __launch_bounds__(256) void bscan_kernel(
        const int* __restrict__ bh, int* __restrict__ offs, int* __restrict__ btot,
        int NB, int NBKT) {
    const int lane = threadIdx.x & 63;
    const int w = blockIdx.x * 4 + (threadIdx.x >> 6);
    if (w >= NBKT) return;
    int running = 0;
    for (int base = 0; base < NB; base += 64) {
        const int j = base + lane;
        const int v = (j < NB) ? bh[w * NB + j] : 0;
        int incl = v;
#pragma unroll
        for (int off = 1; off < 64; off <<= 1) {
            const int t = __shfl_up(incl, off);
            if (lane >= off) incl += t;
        }
        if (j < NB) offs[w * NB + j] = running + incl - v;
        running += __shfl(incl, 63);
    }
    if (lane == 0) btot[w] = running;
}

__global__ __launch_bounds__(64) void bucketbase_kernel(
        const int* __restrict__ btot, int* __restrict__ bucket_base, int NBKT) {
    const int lane = threadIdx.x;
    int running = 0;
    for (int base = 0; base < NBKT; base += 64) {
        const int j = base + lane;
        const int v = (j < NBKT) ? btot[j] : 0;
        int incl = v;
#pragma unroll
        for (int off = 1; off < 64; off <<= 1) {
            const int t = __shfl_up(incl, off);
            if (lane >= off) incl += t;
        }
        if (j < NBKT) bucket_base[j] = running + incl - v;
        running += __shfl(incl, 63);
    }
    if (lane == 0) bucket_base[NBKT] = running;
}

__global__ __launch_bounds__(256) void scatter_kernel(
        const int* __restrict__ ei, const int* __restrict__ offs,
        const int* __restrict__ bucket_base, unsigned* __restrict__ ebuf,
        int E, int NB, int NBKT) {
    __shared__ int lcur[256];
    const int tid = threadIdx.x, blk = blockIdx.x;
    if (tid < NBKT) lcur[tid] = bucket_base[tid] + offs[tid * NB + blk];
    __syncthreads();
    const int base = blk << 12;
#pragma unroll
    for (int i = 0; i < 16; ++i) {
        const int e = base + (i << 8) + tid;
        if (e < E) {
            const int s = ei[e];
            const unsigned d = (unsigned)ei[E + e];
            int p = atomicAdd(&lcur[min((int)(d >> 9), NBKT - 1)], 1);
            p = min(p, E - 1);                       // defensive
            ebuf[p] = ((d & 511u) << 17) | (unsigned)s;
        }
    }
}

__global__ __launch_bounds__(512) void bucket_csr_kernel(
        const unsigned* __restrict__ ebuf, const int* __restrict__ bucket_base,
        int* __restrict__ rowptr, int* __restrict__ deg, int* __restrict__ col,
        int N, int E) {
    __shared__ int ldeg[512];
    __shared__ int buf[512];
    __shared__ int lcur[512];
    const int b = blockIdx.x, tid = threadIdx.x;
    const int segbase = bucket_base[b];
    const int L = bucket_base[b + 1] - segbase;
    ldeg[tid] = 0;
    __syncthreads();
    for (int i = tid; i < L; i += 512) atomicAdd(&ldeg[ebuf[segbase + i] >> 17], 1);
    __syncthreads();
    buf[tid] = ldeg[tid];
    __syncthreads();
    for (int off = 1; off < 512; off <<= 1) {
        const int t = (tid >= off) ? buf[tid - off] : 0;
        __syncthreads();
        buf[tid] += t;
        __syncthreads();
    }
    const int excl = buf[tid] - ldeg[tid];
    const int node = (b << 9) + tid;
    if (node < N) { rowptr[node] = segbase + excl; deg[node] = ldeg[tid]; }
    lcur[tid] = excl;
    __syncthreads();
    for (int i = tid; i < L; i += 512) {
        const unsigned p = ebuf[segbase + i];
        int pos = atomicAdd(&lcur[p >> 17], 1);
        pos = min(segbase + pos, E - 1);             // defensive
        col[pos] = (int)(p & 0x1FFFFu);
    }
}

// ---------------- MFMA transform: y_l = A@Wl (fp8|bf16), y_r = A@Wr+b (bf16) -
template <int K, int F_OUT, int PAD, bool AFP32, bool YL8>
__global__ __launch_bounds__(256) void transform_kernel(
        const void* __restrict__ Ain, const float* __restrict__ Wl,
        const float* __restrict__ Wr, const float* __restrict__ b,
        void* __restrict__ yl, unsigned short* __restrict__ yr, int n) {
    constexpr int KSTEP = K / 32;
    constexpr int NT = PAD / 16;
    const int lane = threadIdx.x & 63;
    const int wid = (blockIdx.x * blockDim.x + threadIdx.x) >> 6;
    const int ntiles = (n + 15) >> 4;
    if (wid >= ntiles) return;
    const int nl = lane & 15, q = lane >> 4;

    short8 Bl[NT][KSTEP], Br[NT][KSTEP];
    float biasv[NT];
#pragma unroll
    for (int t = 0; t < NT; ++t) {
        const int ncol = t * 16 + nl;
        biasv[t] = (ncol < F_OUT) ? b[ncol] : 0.f;
#pragma unroll
        for (int ks = 0; ks < KSTEP; ++ks) {
#pragma unroll
            for (int j = 0; j < 8; ++j) {
                const int k = ks * 32 + q * 8 + j;
                Bl[t][ks][j] = (ncol < F_OUT) ? (short)f2bf(Wl[k * F_OUT + ncol]) : (short)0;
                Br[t][ks][j] = (ncol < F_OUT) ? (short)f2bf(Wr[k * F_OUT + ncol]) : (short)0;
            }
        }
    }

    const int m0 = wid * 16;
    int m = m0 + nl; if (m >= n) m = n - 1;

    short8 a[KSTEP];
#pragma unroll
    for (int ks = 0; ks < KSTEP; ++ks) {
        if (AFP32) {
            const float* p = (const float*)Ain + (size_t)m * K + ks * 32 + q * 8;
#pragma unroll
            for (int j = 0; j < 8; ++j) a[ks][j] = (short)f2bf(p[j]);
        } else {
            union { uint4 u; short8 s; } cvt;
            cvt.u = *(const uint4*)((const unsigned short*)Ain + (size_t)m * K + ks * 32 + q * 8);
            a[ks] = cvt.s;
        }
    }

    floatx4 accl[NT], accr[NT];
#pragma unroll
    for (int t = 0; t < NT; ++t) { accl[t] = {0.f,0.f,0.f,0.f}; accr[t] = {0.f,0.f,0.f,0.f}; }
#pragma unroll
    for (int ks = 0; ks < KSTEP; ++ks) {
#pragma unroll
        for (int t = 0; t < NT; ++t) {
            accl[t] = __builtin_amdgcn_mfma_f32_16x16x32_bf16(a[ks], Bl[t][ks], accl[t], 0, 0, 0);
            accr[t] = __builtin_amdgcn_mfma_f32_16x16x32_bf16(a[ks], Br[t][ks], accr[t], 0, 0, 0);
        }
    }

#pragma unroll
    for (int t = 0; t < NT; ++t) {
        const int ncol = t * 16 + nl;
#pragma unroll
        for (int r = 0; r < 4; ++r) {
            const int node = m0 + q * 4 + r;
            if (node < n) {
                if (YL8)
                    ((unsigned char*)yl)[(size_t)node * PAD + ncol] = f2fp8(accl[t][r]);
                else
                    ((unsigned short*)yl)[(size_t)node * PAD + ncol] = f2bf(accl[t][r]);
                yr[(size_t)node * PAD + ncol] = f2bf(accr[t][r] + biasv[t]);
            }
        }
    }
}

// ---------------- aggregate: h = act(norm(mean_gather(yl) + yr)) ------------
// PK: 0 = bf16 payload (uint4/row-chunk), 1 = fp8 payload (uint2/row-chunk).
template <int F, int ACT, int PK>
__global__ __launch_bounds__(256) void agg_kernel(
        const void* __restrict__ yl, const unsigned short* __restrict__ yr,
        const int* __restrict__ rowptr, const int* __restrict__ degv,
        const int* __restrict__ col,
        unsigned short* __restrict__ hout, float* __restrict__ fout, int n) {
    constexpr int G = F / 8;
    constexpr int NPW = 64 / G;
    const int lane = threadIdx.x & 63;
    const int wid = (blockIdx.x * blockDim.x + threadIdx.x) >> 6;
    const int g = lane / G, c = lane % G;
    const int node = wid * NPW + g;
    if (node >= n) return;

    const int beg = rowptr[node];
    const int dg  = degv[node];
    const int nmax = n - 1;

    float a0=0.f,a1=0.f,a2=0.f,a3=0.f,a4=0.f,a5=0.f,a6=0.f,a7=0.f;
    int i = 0;
    if (PK == 1) {
        const unsigned char* base = (const unsigned char*)yl + c * 8;
        auto accrow = [&](uint2 t) {
            const floatx2 p0 = __builtin_amdgcn_cvt_pk_f32_fp8((int)t.x, false);
            const floatx2 p1 = __builtin_amdgcn_cvt_pk_f32_fp8((int)t.x, true);
            const floatx2 p2 = __builtin_amdgcn_cvt_pk_f32_fp8((int)t.y, false);
            const floatx2 p3 = __builtin_amdgcn_cvt_pk_f32_fp8((int)t.y, true);
            a0 += p0.x; a1 += p0.y; a2 += p1.x; a3 += p1.y;
            a4 += p2.x; a5 += p2.y; a6 += p3.x; a7 += p3.y;
        };
        for (; i + 4 <= dg; i += 4) {
            const int n0 = min(col[beg + i],     nmax);
            const int n1 = min(col[beg + i + 1], nmax);
            const int n2 = min(col[beg + i + 2], nmax);
            const int n3 = min(col[beg + i + 3], nmax);
            const uint2 t0 = *(const uint2*)(base + (size_t)n0 * F);
            const uint2 t1 = *(const uint2*)(base + (size_t)n1 * F);
            const uint2 t2 = *(const uint2*)(base + (size_t)n2 * F);
            const uint2 t3 = *(const uint2*)(base + (size_t)n3 * F);
            accrow(t0); accrow(t1); accrow(t2); accrow(t3);
        }
        for (; i < dg; ++i) {
            const int n0 = min(col[beg + i], nmax);
            accrow(*(const uint2*)(base + (size_t)n0 * F));
        }
    } else {
        const unsigned short* base = (const unsigned short*)yl + c * 8;
        for (; i + 4 <= dg; i += 4) {
            const int n0 = min(col[beg + i],     nmax);
            const int n1 = min(col[beg + i + 1], nmax);
            const int n2 = min(col[beg + i + 2], nmax);
            const int n3 = min(col[beg + i + 3], nmax);
            const uint4 t0 = *(const uint4*)(base + (size_t)n0 * F);
            const uint4 t1 = *(const uint4*)(base + (size_t)n1 * F);
            const uint4 t2 = *(const uint4*)(base + (size_t)n2 * F);
            const uint4 t3 = *(const uint4*)(base + (size_t)n3 * F);
            a0 += blo(t0.x) + blo(t1.x) + blo(t2.x) + blo(t3.x);
            a1 += bhi(t0.x) + bhi(t1.x) + bhi(t2.x) + bhi(t3.x);
            a2 += blo(t0.y) + blo(t1.y) + blo(t2.y) + blo(t3.y);
            a3 += bhi(t0.y) + bhi(t1.y) + bhi(t2.y) + bhi(t3.y);
            a4 += blo(t0.z) + blo(t1.z) + blo(t2.z) + blo(t3.z);
            a5 += bhi(t0.z) + bhi(t1.z) + bhi(t2.z) + bhi(t3.z);
            a6 += blo(t0.w) + blo(t1.w) + blo(t2.w) + blo(t3.w);
            a7 += bhi(t0.w) + bhi(t1.w) + bhi(t2.w) + bhi(t3.w);
        }
        for (; i < dg; ++i) {
            const int n0 = min(col[beg + i], nmax);
            const uint4 t0 = *(const uint4*)(base + (size_t)n0 * F);
            a0 += blo(t0.x); a1 += bhi(t0.x); a2 += blo(t0.y); a3 += bhi(t0.y);
            a4 += blo(t0.z); a5 += bhi(t0.z); a6 += blo(t0.w); a7 += bhi(t0.w);
        }
    }
    const float inv = (dg > 0) ? 1.f / (float)dg : 0.f;

    // yr residual: bf16, coalesced
    const uint4 rv = *(const uint4*)(yr + (size_t)node * F + c * 8);
    float o[8];
    o[0] = a0*inv + blo(rv.x); o[1] = a1*inv + bhi(rv.x);
    o[2] = a2*inv + blo(rv.y); o[3] = a3*inv + bhi(rv.y);
    o[4] = a4*inv + blo(rv.z); o[5] = a5*inv + bhi(rv.z);
    o[6] = a6*inv + blo(rv.w); o[7] = a7*inv + bhi(rv.w);

    float ss = 0.f;
#pragma unroll
    for (int j = 0; j < 8; ++j) ss += o[j] * o[j];
#pragma unroll
    for (int off = 1; off < G; off <<= 1) ss += __shfl_xor(ss, off);
    const float scale = 1.f / fmaxf(sqrtf(ss), 1e-12f);

    if (ACT == 1) {
        uint4 u;
        float h[8];
#pragma unroll
        for (int j = 0; j < 8; ++j) h[j] = fmaxf(o[j] * scale, 0.f);
        u.x = (unsigned)f2bf(h[0]) | ((unsigned)f2bf(h[1]) << 16);
        u.y = (unsigned)f2bf(h[2]) | ((unsigned)f2bf(h[3]) << 16);
        u.z = (unsigned)f2bf(h[4]) | ((unsigned)f2bf(h[5]) << 16);
        u.w = (unsigned)f2bf(h[6]) | ((unsigned)f2bf(h[7]) << 16);
        *(uint4*)(hout + (size_t)node * F + c * 8) = u;
    } else {
#pragma unroll
        for (int j = 0; j < 8; ++j) o[j] *= scale;
        const int cbase = c * 8;
        float m = -INFINITY;
#pragma unroll
        for (int j = 0; j < 8; ++j) if (cbase + j < 10) m = fmaxf(m, o[j]);
        m = fmaxf(m, __shfl_xor(m, 1));
        float s = 0.f;
#pragma unroll
        for (int j = 0; j < 8; ++j) if (cbase + j < 10) s += __expf(o[j] - m);
        s += __shfl_xor(s, 1);
        const float ls = logf(s);
#pragma unroll
        for (int j = 0; j < 8; ++j)
            if (cbase + j < 10) fout[(size_t)node * 10 + cbase + j] = o[j] - m - ls;
    }
}

extern "C" void kernel_launch(void* const* d_in, const int* in_sizes, int n_in,
                              void* d_out, int out_size, void* d_ws, size_t ws_size,
                              hipStream_t stream) {
    const float* x   = (const float*)d_in[0];
    const int*   ei  = (const int*)d_in[1];     // int64 in ref -> int32 on device
    const float* W1l = (const float*)d_in[2];
    const float* W1r = (const float*)d_in[3];
    const float* b1  = (const float*)d_in[4];
    const float* W2l = (const float*)d_in[5];
    const float* W2r = (const float*)d_in[6];
    const float* b2  = (const float*)d_in[7];
    const float* W3l = (const float*)d_in[8];
    const float* W3r = (const float*)d_in[9];
    const float* b3  = (const float*)d_in[10];
    float*       out = (float*)d_out;

    const int N = in_sizes[0] / 64;
    const int E = in_sizes[1] / 2;
    const int NBKT = (N + 511) >> 9;     // dst buckets of 512 nodes (<=256)
    const int NB   = (E + 4095) >> 12;   // 4096 edges per hist/scatter block

    auto align16 = [](size_t v) { return (v + 15) & ~(size_t)15; };
    char* ws = (char*)d_ws;
    size_t off = 0;
    int* rowptr  = (int*)(ws + off); off = align16(off + (size_t)N * 4);
    int* deg     = (int*)(ws + off); off = align16(off + (size_t)N * 4);
    int* colidx  = (int*)(ws + off); off = align16(off + (size_t)E * 4);
    unsigned* ebuf = (unsigned*)(ws + off); off = align16(off + (size_t)E * 4);
    int* bh      = (int*)(ws + off); off = align16(off + (size_t)NBKT * NB * 4);
    int* offsb   = (int*)(ws + off); off = align16(off + (size_t)NBKT * NB * 4);
    int* btot    = (int*)(ws + off); off = align16(off + (size_t)NBKT * 4);
    int* bbase   = (int*)(ws + off); off = align16(off + (size_t)(NBKT + 1) * 4);
    unsigned char*  y1l = (unsigned char*)(ws + off);  off = align16(off + (size_t)N * 64);
    unsigned short* y1r = (unsigned short*)(ws + off); off = align16(off + (size_t)N * 64 * 2);
    unsigned short* h1  = (unsigned short*)(ws + off); off = align16(off + (size_t)N * 64 * 2);
    unsigned short* y2l = (unsigned short*)(ws + off); off = align16(off + (size_t)N * 32 * 2);
    unsigned short* y2r = (unsigned short*)(ws + off); off = align16(off + (size_t)N * 32 * 2);
    unsigned short* h2  = (unsigned short*)(ws + off); off = align16(off + (size_t)N * 32 * 2);
    unsigned short* y3l = (unsigned short*)(ws + off); off = align16(off + (size_t)N * 16 * 2);
    unsigned short* y3r = (unsigned short*)(ws + off); off = align16(off + (size_t)N * 16 * 2);
    (void)ws_size; (void)n_in; (void)out_size;

    // ---- CSR build (atomic-free bucket sort)
    hist_kernel<<<NB, 256, 0, stream>>>(ei, bh, E, NB, NBKT);
    bscan_kernel<<<(NBKT + 3) / 4, 256, 0, stream>>>(bh, offsb, btot, NB, NBKT);
    bucketbase_kernel<<<1, 64, 0, stream>>>(btot, bbase, NBKT);
    scatter_kernel<<<NB, 256, 0, stream>>>(ei, offsb, bbase, ebuf, E, NB, NBKT);
    bucket_csr_kernel<<<NBKT, 512, 0, stream>>>(ebuf, bbase, rowptr, deg, colidx, N, E);

    const int ntiles = (N + 15) / 16;                  // MFMA node tiles
    const int tblocks = (ntiles * 64 + 255) / 256;     // 4 waves/block

    // layer 1 (fp8 gather payload)
    transform_kernel<64, 64, 64, true, true><<<tblocks, 256, 0, stream>>>(
        x, W1l, W1r, b1, y1l, y1r, N);
    agg_kernel<64, 1, 1><<<(N + 31) / 32, 256, 0, stream>>>(
        y1l, y1r, rowptr, deg, colidx, h1, nullptr, N);
    // layer 2 (bf16 payload)
    transform_kernel<64, 32, 32, false, false><<<tblocks, 256, 0, stream>>>(
        h1, W2l, W2r, b2, y2l, y2r, N);
    agg_kernel<32, 1, 0><<<(N + 63) / 64, 256, 0, stream>>>(
        y2l, y2r, rowptr, deg, colidx, h2, nullptr, N);
    // layer 3 (bf16 payload)
    transform_kernel<32, 10, 16, false, false><<<tblocks, 256, 0, stream>>>(
        h2, W3l, W3r, b3, y3l, y3r, N);
    agg_kernel<16, 2, 0><<<(N + 127) / 128, 256, 0, stream>>>(
        y3l, y3r, rowptr, deg, colidx, nullptr, out, N);
}

// Round 12
// 215.009 us; speedup vs baseline: 1.3101x; 1.0332x over previous
//
#include <hip/hip_runtime.h>
#include <math.h>

// ---------------------------------------------------------------------------
// GraphSAGE 3-layer forward.
//  - transforms: MFMA bf16 GEMM (16 nodes/wave); gather payloads y1l AND y2l
//    stored FP8 e4m3 (R11/R12: random-gather working sets 12.8/6.4MB drop to
//    6.4/3.2MB — below the 4MB per-XCD L2 wall — and logical bytes halve;
//    HW cvt_pk_f32_fp8 decode). y3l stays bf16 (L2-resident; precision reserve).
//    yr residuals bf16 (streamed once, coalesced).
//  - aggregates: sub-wave-per-node register accumulation, consecutive nodes,
//    unroll-4 (R10: concurrency beyond this is NOT the limiter — ~3.4TB/s
//    random-gather ceiling; fewer/hotter bytes is the lever).
//  - CSR build: atomic-free 2-level bucket sort (R7) + defensive clamps (R10).
// Assumes N <= 2^17 and ceil(N/512) <= 256.
// ---------------------------------------------------------------------------

typedef __attribute__((ext_vector_type(8))) short short8;
typedef __attribute__((ext_vector_type(4))) float floatx4;
typedef __attribute__((ext_vector_type(2))) float floatx2;

__device__ __forceinline__ unsigned short f2bf(float f) {   // RNE
    unsigned u = __float_as_uint(f);
    u += 0x7fffu + ((u >> 16) & 1u);
    return (unsigned short)(u >> 16);
}
__device__ __forceinline__ float blo(unsigned u) { return __uint_as_float(u << 16); }
__device__ __forceinline__ float bhi(unsigned u) { return __uint_as_float(u & 0xffff0000u); }
__device__ __forceinline__ unsigned char f2fp8(float f) {   // e4m3fn via HW
    return (unsigned char)(__builtin_amdgcn_cvt_pk_fp8_f32(f, f, 0, false) & 0xFF);
}

// ---------------- CSR build (bucketed, atomic-free at global scope) ---------

__global__ __launch_bounds__(256) void hist_kernel(
        const int* __restrict__ ei, int* __restrict__ bh, int E, int NB, int NBKT) {
    __shared__ int lh[256];
    const int tid = threadIdx.x, blk = blockIdx.x;
    lh[tid] = 0;
    __syncthreads();
    const int base = blk << 12;
#pragma unroll
    for (int i = 0; i < 16; ++i) {
        const int e = base + (i << 8) + tid;
        if (e < E) atomicAdd(&lh[min((int)(((unsigned)ei[E + e]) >> 9), NBKT - 1)], 1);
    }
    __syncthreads();
    if (tid < NBKT) bh[tid * NB + blk] = lh[tid];
}

__global__ __launch_bounds__(256) void bscan_kernel(
        const int* __restrict__ bh, int* __restrict__ offs, int* __restrict__ btot,
        int NB, int NBKT) {
    const int lane = threadIdx.x & 63;
    const int w = blockIdx.x * 4 + (threadIdx.x >> 6);
    if (w >= NBKT) return;
    int running = 0;
    for (int base = 0; base < NB; base += 64) {
        const int j = base + lane;
        const int v = (j < NB) ? bh[w * NB + j] : 0;
        int incl = v;
#pragma unroll
        for (int off = 1; off < 64; off <<= 1) {
            const int t = __shfl_up(incl, off);
            if (lane >= off) incl += t;
        }
        if (j < NB) offs[w * NB + j] = running + incl - v;
        running += __shfl(incl, 63);
    }
    if (lane == 0) btot[w] = running;
}

__global__ __launch_bounds__(64) void bucketbase_kernel(
        const int* __restrict__ btot, int* __restrict__ bucket_base, int NBKT) {
    const int lane = threadIdx.x;
    int running = 0;
    for (int base = 0; base < NBKT; base += 64) {
        const int j = base + lane;
        const int v = (j < NBKT) ? btot[j] : 0;
        int incl = v;
#pragma unroll
        for (int off = 1; off < 64; off <<= 1) {
            const int t = __shfl_up(incl, off);
            if (lane >= off) incl += t;
        }
        if (j < NBKT) bucket_base[j] = running + incl - v;
        running += __shfl(incl, 63);
    }
    if (lane == 0) bucket_base[NBKT] = running;
}

__global__ __launch_bounds__(256) void scatter_kernel(
        const int* __restrict__ ei, const int* __restrict__ offs,
        const int* __restrict__ bucket_base, unsigned* __restrict__ ebuf,
        int E, int NB, int NBKT) {
    __shared__ int lcur[256];
    const int tid = threadIdx.x, blk = blockIdx.x;
    if (tid < NBKT) lcur[tid] = bucket_base[tid] + offs[tid * NB + blk];
    __syncthreads();
    const int base = blk << 12;
#pragma unroll
    for (int i = 0; i < 16; ++i) {
        const int e = base + (i << 8) + tid;
        if (e < E) {
            const int s = ei[e];
            const unsigned d = (unsigned)ei[E + e];
            int p = atomicAdd(&lcur[min((int)(d >> 9), NBKT - 1)], 1);
            p = min(p, E - 1);                       // defensive
            ebuf[p] = ((d & 511u) << 17) | (unsigned)s;
        }
    }
}

__global__ __launch_bounds__(512) void bucket_csr_kernel(
        const unsigned* __restrict__ ebuf, const int* __restrict__ bucket_base,
        int* __restrict__ rowptr, int* __restrict__ deg, int* __restrict__ col,
        int N, int E) {
    __shared__ int ldeg[512];
    __shared__ int buf[512];
    __shared__ int lcur[512];
    const int b = blockIdx.x, tid = threadIdx.x;
    const int segbase = bucket_base[b];
    const int L = bucket_base[b + 1] - segbase;
    ldeg[tid] = 0;
    __syncthreads();
    for (int i = tid; i < L; i += 512) atomicAdd(&ldeg[ebuf[segbase + i] >> 17], 1);
    __syncthreads();
    buf[tid] = ldeg[tid];
    __syncthreads();
    for (int off = 1; off < 512; off <<= 1) {
        const int t = (tid >= off) ? buf[tid - off] : 0;
        __syncthreads();
        buf[tid] += t;
        __syncthreads();
    }
    const int excl = buf[tid] - ldeg[tid];
    const int node = (b << 9) + tid;
    if (node < N) { rowptr[node] = segbase + excl; deg[node] = ldeg[tid]; }
    lcur[tid] = excl;
    __syncthreads();
    for (int i = tid; i < L; i += 512) {
        const unsigned p = ebuf[segbase + i];
        int pos = atomicAdd(&lcur[p >> 17], 1);
        pos = min(segbase + pos, E - 1);             // defensive
        col[pos] = (int)(p & 0x1FFFFu);
    }
}

// ---------------- MFMA transform: y_l = A@Wl (fp8|bf16), y_r = A@Wr+b (bf16) -
template <int K, int F_OUT, int PAD, bool AFP32, bool YL8>
__global__ __launch_bounds__(256) void transform_kernel(
        const void* __restrict__ Ain, const float* __restrict__ Wl,
        const float* __restrict__ Wr, const float* __restrict__ b,
        void* __restrict__ yl, unsigned short* __restrict__ yr, int n) {
    constexpr int KSTEP = K / 32;
    constexpr int NT = PAD / 16;
    const int lane = threadIdx.x & 63;
    const int wid = (blockIdx.x * blockDim.x + threadIdx.x) >> 6;
    const int ntiles = (n + 15) >> 4;
    if (wid >= ntiles) return;
    const int nl = lane & 15, q = lane >> 4;

    short8 Bl[NT][KSTEP], Br[NT][KSTEP];
    float biasv[NT];
#pragma unroll
    for (int t = 0; t < NT; ++t) {
        const int ncol = t * 16 + nl;
        biasv[t] = (ncol < F_OUT) ? b[ncol] : 0.f;
#pragma unroll
        for (int ks = 0; ks < KSTEP; ++ks) {
#pragma unroll
            for (int j = 0; j < 8; ++j) {
                const int k = ks * 32 + q * 8 + j;
                Bl[t][ks][j] = (ncol < F_OUT) ? (short)f2bf(Wl[k * F_OUT + ncol]) : (short)0;
                Br[t][ks][j] = (ncol < F_OUT) ? (short)f2bf(Wr[k * F_OUT + ncol]) : (short)0;
            }
        }
    }

    const int m0 = wid * 16;
    int m = m0 + nl; if (m >= n) m = n - 1;

    short8 a[KSTEP];
#pragma unroll
    for (int ks = 0; ks < KSTEP; ++ks) {
        if (AFP32) {
            const float* p = (const float*)Ain + (size_t)m * K + ks * 32 + q * 8;
#pragma unroll
            for (int j = 0; j < 8; ++j) a[ks][j] = (short)f2bf(p[j]);
        } else {
            union { uint4 u; short8 s; } cvt;
            cvt.u = *(const uint4*)((const unsigned short*)Ain + (size_t)m * K + ks * 32 + q * 8);
            a[ks] = cvt.s;
        }
    }

    floatx4 accl[NT], accr[NT];
#pragma unroll
    for (int t = 0; t < NT; ++t) { accl[t] = {0.f,0.f,0.f,0.f}; accr[t] = {0.f,0.f,0.f,0.f}; }
#pragma unroll
    for (int ks = 0; ks < KSTEP; ++ks) {
#pragma unroll
        for (int t = 0; t < NT; ++t) {
            accl[t] = __builtin_amdgcn_mfma_f32_16x16x32_bf16(a[ks], Bl[t][ks], accl[t], 0, 0, 0);
            accr[t] = __builtin_amdgcn_mfma_f32_16x16x32_bf16(a[ks], Br[t][ks], accr[t], 0, 0, 0);
        }
    }

#pragma unroll
    for (int t = 0; t < NT; ++t) {
        const int ncol = t * 16 + nl;
#pragma unroll
        for (int r = 0; r < 4; ++r) {
            const int node = m0 + q * 4 + r;
            if (node < n) {
                if (YL8)
                    ((unsigned char*)yl)[(size_t)node * PAD + ncol] = f2fp8(accl[t][r]);
                else
                    ((unsigned short*)yl)[(size_t)node * PAD + ncol] = f2bf(accl[t][r]);
                yr[(size_t)node * PAD + ncol] = f2bf(accr[t][r] + biasv[t]);
            }
        }
    }
}

// ---------------- aggregate: h = act(norm(mean_gather(yl) + yr)) ------------
// PK: 0 = bf16 payload (uint4/row-chunk), 1 = fp8 payload (uint2/row-chunk).
template <int F, int ACT, int PK>
__global__ __launch_bounds__(256) void agg_kernel(
        const void* __restrict__ yl, const unsigned short* __restrict__ yr,
        const int* __restrict__ rowptr, const int* __restrict__ degv,
        const int* __restrict__ col,
        unsigned short* __restrict__ hout, float* __restrict__ fout, int n) {
    constexpr int G = F / 8;
    constexpr int NPW = 64 / G;
    const int lane = threadIdx.x & 63;
    const int wid = (blockIdx.x * blockDim.x + threadIdx.x) >> 6;
    const int g = lane / G, c = lane % G;
    const int node = wid * NPW + g;
    if (node >= n) return;

    const int beg = rowptr[node];
    const int dg  = degv[node];
    const int nmax = n - 1;

    float a0=0.f,a1=0.f,a2=0.f,a3=0.f,a4=0.f,a5=0.f,a6=0.f,a7=0.f;
    int i = 0;
    if (PK == 1) {
        const unsigned char* base = (const unsigned char*)yl + c * 8;
        auto accrow = [&](uint2 t) {
            const floatx2 p0 = __builtin_amdgcn_cvt_pk_f32_fp8((int)t.x, false);
            const floatx2 p1 = __builtin_amdgcn_cvt_pk_f32_fp8((int)t.x, true);
            const floatx2 p2 = __builtin_amdgcn_cvt_pk_f32_fp8((int)t.y, false);
            const floatx2 p3 = __builtin_amdgcn_cvt_pk_f32_fp8((int)t.y, true);
            a0 += p0.x; a1 += p0.y; a2 += p1.x; a3 += p1.y;
            a4 += p2.x; a5 += p2.y; a6 += p3.x; a7 += p3.y;
        };
        for (; i + 4 <= dg; i += 4) {
            const int n0 = min(col[beg + i],     nmax);
            const int n1 = min(col[beg + i + 1], nmax);
            const int n2 = min(col[beg + i + 2], nmax);
            const int n3 = min(col[beg + i + 3], nmax);
            const uint2 t0 = *(const uint2*)(base + (size_t)n0 * F);
            const uint2 t1 = *(const uint2*)(base + (size_t)n1 * F);
            const uint2 t2 = *(const uint2*)(base + (size_t)n2 * F);
            const uint2 t3 = *(const uint2*)(base + (size_t)n3 * F);
            accrow(t0); accrow(t1); accrow(t2); accrow(t3);
        }
        for (; i < dg; ++i) {
            const int n0 = min(col[beg + i], nmax);
            accrow(*(const uint2*)(base + (size_t)n0 * F));
        }
    } else {
        const unsigned short* base = (const unsigned short*)yl + c * 8;
        for (; i + 4 <= dg; i += 4) {
            const int n0 = min(col[beg + i],     nmax);
            const int n1 = min(col[beg + i + 1], nmax);
            const int n2 = min(col[beg + i + 2], nmax);
            const int n3 = min(col[beg + i + 3], nmax);
            const uint4 t0 = *(const uint4*)(base + (size_t)n0 * F);
            const uint4 t1 = *(const uint4*)(base + (size_t)n1 * F);
            const uint4 t2 = *(const uint4*)(base + (size_t)n2 * F);
            const uint4 t3 = *(const uint4*)(base + (size_t)n3 * F);
            a0 += blo(t0.x) + blo(t1.x) + blo(t2.x) + blo(t3.x);
            a1 += bhi(t0.x) + bhi(t1.x) + bhi(t2.x) + bhi(t3.x);
            a2 += blo(t0.y) + blo(t1.y) + blo(t2.y) + blo(t3.y);
            a3 += bhi(t0.y) + bhi(t1.y) + bhi(t2.y) + bhi(t3.y);
            a4 += blo(t0.z) + blo(t1.z) + blo(t2.z) + blo(t3.z);
            a5 += bhi(t0.z) + bhi(t1.z) + bhi(t2.z) + bhi(t3.z);
            a6 += blo(t0.w) + blo(t1.w) + blo(t2.w) + blo(t3.w);
            a7 += bhi(t0.w) + bhi(t1.w) + bhi(t2.w) + bhi(t3.w);
        }
        for (; i < dg; ++i) {
            const int n0 = min(col[beg + i], nmax);
            const uint4 t0 = *(const uint4*)(base + (size_t)n0 * F);
            a0 += blo(t0.x); a1 += bhi(t0.x); a2 += blo(t0.y); a3 += bhi(t0.y);
            a4 += blo(t0.z); a5 += bhi(t0.z); a6 += blo(t0.w); a7 += bhi(t0.w);
        }
    }
    const float inv = (dg > 0) ? 1.f / (float)dg : 0.f;

    // yr residual: bf16, coalesced
    const uint4 rv = *(const uint4*)(yr + (size_t)node * F + c * 8);
    float o[8];
    o[0] = a0*inv + blo(rv.x); o[1] = a1*inv + bhi(rv.x);
    o[2] = a2*inv + blo(rv.y); o[3] = a3*inv + bhi(rv.y);
    o[4] = a4*inv + blo(rv.z); o[5] = a5*inv + bhi(rv.z);
    o[6] = a6*inv + blo(rv.w); o[7] = a7*inv + bhi(rv.w);

    float ss = 0.f;
#pragma unroll
    for (int j = 0; j < 8; ++j) ss += o[j] * o[j];
#pragma unroll
    for (int off = 1; off < G; off <<= 1) ss += __shfl_xor(ss, off);
    const float scale = 1.f / fmaxf(sqrtf(ss), 1e-12f);

    if (ACT == 1) {
        uint4 u;
        float h[8];
#pragma unroll
        for (int j = 0; j < 8; ++j) h[j] = fmaxf(o[j] * scale, 0.f);
        u.x = (unsigned)f2bf(h[0]) | ((unsigned)f2bf(h[1]) << 16);
        u.y = (unsigned)f2bf(h[2]) | ((unsigned)f2bf(h[3]) << 16);
        u.z = (unsigned)f2bf(h[4]) | ((unsigned)f2bf(h[5]) << 16);
        u.w = (unsigned)f2bf(h[6]) | ((unsigned)f2bf(h[7]) << 16);
        *(uint4*)(hout + (size_t)node * F + c * 8) = u;
    } else {
#pragma unroll
        for (int j = 0; j < 8; ++j) o[j] *= scale;
        const int cbase = c * 8;
        float m = -INFINITY;
#pragma unroll
        for (int j = 0; j < 8; ++j) if (cbase + j < 10) m = fmaxf(m, o[j]);
        m = fmaxf(m, __shfl_xor(m, 1));
        float s = 0.f;
#pragma unroll
        for (int j = 0; j < 8; ++j) if (cbase + j < 10) s += __expf(o[j] - m);
        s += __shfl_xor(s, 1);
        const float ls = logf(s);
#pragma unroll
        for (int j = 0; j < 8; ++j)
            if (cbase + j < 10) fout[(size_t)node * 10 + cbase + j] = o[j] - m - ls;
    }
}

extern "C" void kernel_launch(void* const* d_in, const int* in_sizes, int n_in,
                              void* d_out, int out_size, void* d_ws, size_t ws_size,
                              hipStream_t stream) {
    const float* x   = (const float*)d_in[0];
    const int*   ei  = (const int*)d_in[1];     // int64 in ref -> int32 on device
    const float* W1l = (const float*)d_in[2];
    const float* W1r = (const float*)d_in[3];
    const float* b1  = (const float*)d_in[4];
    const float* W2l = (const float*)d_in[5];
    const float* W2r = (const float*)d_in[6];
    const float* b2  = (const float*)d_in[7];
    const float* W3l = (const float*)d_in[8];
    const float* W3r = (const float*)d_in[9];
    const float* b3  = (const float*)d_in[10];
    float*       out = (float*)d_out;

    const int N = in_sizes[0] / 64;
    const int E = in_sizes[1] / 2;
    const int NBKT = (N + 511) >> 9;     // dst buckets of 512 nodes (<=256)
    const int NB   = (E + 4095) >> 12;   // 4096 edges per hist/scatter block

    auto align16 = [](size_t v) { return (v + 15) & ~(size_t)15; };
    char* ws = (char*)d_ws;
    size_t off = 0;
    int* rowptr  = (int*)(ws + off); off = align16(off + (size_t)N * 4);
    int* deg     = (int*)(ws + off); off = align16(off + (size_t)N * 4);
    int* colidx  = (int*)(ws + off); off = align16(off + (size_t)E * 4);
    unsigned* ebuf = (unsigned*)(ws + off); off = align16(off + (size_t)E * 4);
    int* bh      = (int*)(ws + off); off = align16(off + (size_t)NBKT * NB * 4);
    int* offsb   = (int*)(ws + off); off = align16(off + (size_t)NBKT * NB * 4);
    int* btot    = (int*)(ws + off); off = align16(off + (size_t)NBKT * 4);
    int* bbase   = (int*)(ws + off); off = align16(off + (size_t)(NBKT + 1) * 4);
    unsigned char*  y1l = (unsigned char*)(ws + off);  off = align16(off + (size_t)N * 64);
    unsigned short* y1r = (unsigned short*)(ws + off); off = align16(off + (size_t)N * 64 * 2);
    unsigned short* h1  = (unsigned short*)(ws + off); off = align16(off + (size_t)N * 64 * 2);
    unsigned char*  y2l = (unsigned char*)(ws + off);  off = align16(off + (size_t)N * 32);
    unsigned short* y2r = (unsigned short*)(ws + off); off = align16(off + (size_t)N * 32 * 2);
    unsigned short* h2  = (unsigned short*)(ws + off); off = align16(off + (size_t)N * 32 * 2);
    unsigned short* y3l = (unsigned short*)(ws + off); off = align16(off + (size_t)N * 16 * 2);
    unsigned short* y3r = (unsigned short*)(ws + off); off = align16(off + (size_t)N * 16 * 2);
    (void)ws_size; (void)n_in; (void)out_size;

    // ---- CSR build (atomic-free bucket sort)
    hist_kernel<<<NB, 256, 0, stream>>>(ei, bh, E, NB, NBKT);
    bscan_kernel<<<(NBKT + 3) / 4, 256, 0, stream>>>(bh, offsb, btot, NB, NBKT);
    bucketbase_kernel<<<1, 64, 0, stream>>>(btot, bbase, NBKT);
    scatter_kernel<<<NB, 256, 0, stream>>>(ei, offsb, bbase, ebuf, E, NB, NBKT);
    bucket_csr_kernel<<<NBKT, 512, 0, stream>>>(ebuf, bbase, rowptr, deg, colidx, N, E);

    const int ntiles = (N + 15) / 16;                  // MFMA node tiles
    const int tblocks = (ntiles * 64 + 255) / 256;     // 4 waves/block

    // layer 1 (fp8 gather payload)
    transform_kernel<64, 64, 64, true, true><<<tblocks, 256, 0, stream>>>(
        x, W1l, W1r, b1, y1l, y1r, N);
    agg_kernel<64, 1, 1><<<(N + 31) / 32, 256, 0, stream>>>(
        y1l, y1r, rowptr, deg, colidx, h1, nullptr, N);
    // layer 2 (fp8 gather payload)
    transform_kernel<64, 32, 32, false, true><<<tblocks, 256, 0, stream>>>(
        h1, W2l, W2r, b2, y2l, y2r, N);
    agg_kernel<32, 1, 1><<<(N + 63) / 64, 256, 0, stream>>>(
        y2l, y2r, rowptr, deg, colidx, h2, nullptr, N);
    // layer 3 (bf16 payload, L2-resident)
    transform_kernel<32, 10, 16, false, false><<<tblocks, 256, 0, stream>>>(
        h2, W3l, W3r, b3, y3l, y3r, N);
    agg_kernel<16, 2, 0><<<(N + 127) / 128, 256, 0, stream>>>(
        y3l, y3r, rowptr, deg, colidx, nullptr, out, N);
}

// Round 13
// 214.692 us; speedup vs baseline: 1.3121x; 1.0015x over previous
//
#include <hip/hip_runtime.h>
#include <math.h>

// ---------------------------------------------------------------------------
// GraphSAGE 3-layer forward.
//  - transforms: MFMA bf16 GEMM (16 nodes/wave); gather payloads y1l AND y2l
//    stored FP8 e4m3 (R11/R12: working sets below per-XCD 4MB L2 + bytes
//    halved). y3l bf16 (precision reserve). yr residuals bf16.
//  - aggregates: sub-wave-per-node register accumulation, consecutive nodes,
//    unroll-4. R13: CSR rows ordered lo-src-half first -> instantaneous gather
//    working set ~3.2MB per phase (fits one XCD L2) instead of 6.4MB thrash.
//  - CSR build: atomic-free 2-level bucket sort (R7) + defensive clamps (R10)
//    + two-cursor src-half ordering in bucket_csr (R13).
// Assumes N <= 2^17 and ceil(N/512) <= 256.
// ---------------------------------------------------------------------------

typedef __attribute__((ext_vector_type(8))) short short8;
typedef __attribute__((ext_vector_type(4))) float floatx4;
typedef __attribute__((ext_vector_type(2))) float floatx2;

__device__ __forceinline__ unsigned short f2bf(float f) {   // RNE
    unsigned u = __float_as_uint(f);
    u += 0x7fffu + ((u >> 16) & 1u);
    return (unsigned short)(u >> 16);
}
__device__ __forceinline__ float blo(unsigned u) { return __uint_as_float(u << 16); }
__device__ __forceinline__ float bhi(unsigned u) { return __uint_as_float(u & 0xffff0000u); }
__device__ __forceinline__ unsigned char f2fp8(float f) {   // e4m3fn via HW
    return (unsigned char)(__builtin_amdgcn_cvt_pk_fp8_f32(f, f, 0, false) & 0xFF);
}

// ---------------- CSR build (bucketed, atomic-free at global scope) ---------

__global__ __launch_bounds__(256) void hist_kernel(
        const int* __restrict__ ei, int* __restrict__ bh, int E, int NB, int NBKT) {
    __shared__ int lh[256];
    const int tid = threadIdx.x, blk = blockIdx.x;
    lh[tid] = 0;
    __syncthreads();
    const int base = blk << 12;
#pragma unroll
    for (int i = 0; i < 16; ++i) {
        const int e = base + (i << 8) + tid;
        if (e < E) atomicAdd(&lh[min((int)(((unsigned)ei[E + e]) >> 9), NBKT - 1)], 1);
    }
    __syncthreads();
    if (tid < NBKT) bh[tid * NB + blk] = lh[tid];
}

__global__ __launch_bounds__(256) void bscan_kernel(
        const int* __restrict__ bh, int* __restrict__ offs, int* __restrict__ btot,
        int NB, int NBKT) {
    const int lane = threadIdx.x & 63;
    const int w = blockIdx.x * 4 + (threadIdx.x >> 6);
    if (w >= NBKT) return;
    int running = 0;
    for (int base = 0; base < NB; base += 64) {
        const int j = base + lane;
        const int v = (j < NB) ? bh[w * NB + j] : 0;
        int incl = v;
#pragma unroll
        for (int off = 1; off < 64; off <<= 1) {
            const int t = __shfl_up(incl, off);
            if (lane >= off) incl += t;
        }
        if (j < NB) offs[w * NB + j] = running + incl - v;
        running += __shfl(incl, 63);
    }
    if (lane == 0) btot[w] = running;
}

__global__ __launch_bounds__(64) void bucketbase_kernel(
        const int* __restrict__ btot, int* __restrict__ bucket_base, int NBKT) {
    const int lane = threadIdx.x;
    int running = 0;
    for (int base = 0; base < NBKT; base += 64) {
        const int j = base + lane;
        const int v = (j < NBKT) ? btot[j] : 0;
        int incl = v;
#pragma unroll
        for (int off = 1; off < 64; off <<= 1) {
            const int t = __shfl_up(incl, off);
            if (lane >= off) incl += t;
        }
        if (j < NBKT) bucket_base[j] = running + incl - v;
        running += __shfl(incl, 63);
    }
    if (lane == 0) bucket_base[NBKT] = running;
}

__global__ __launch_bounds__(256) void scatter_kernel(
        const int* __restrict__ ei, const int* __restrict__ offs,
        const int* __restrict__ bucket_base, unsigned* __restrict__ ebuf,
        int E, int NB, int NBKT) {
    __shared__ int lcur[256];
    const int tid = threadIdx.x, blk = blockIdx.x;
    if (tid < NBKT) lcur[tid] = bucket_base[tid] + offs[tid * NB + blk];
    __syncthreads();
    const int base = blk << 12;
#pragma unroll
    for (int i = 0; i < 16; ++i) {
        const int e = base + (i << 8) + tid;
        if (e < E) {
            const int s = ei[e];
            const unsigned d = (unsigned)ei[E + e];
            int p = atomicAdd(&lcur[min((int)(d >> 9), NBKT - 1)], 1);
            p = min(p, E - 1);                       // defensive
            ebuf[p] = ((d & 511u) << 17) | (unsigned)s;
        }
    }
}

// R13: per-node two-cursor scatter — all src < half land before src >= half,
// so agg row traversal touches a ~half-sized gather working set per phase.
__global__ __launch_bounds__(512) void bucket_csr_kernel(
        const unsigned* __restrict__ ebuf, const int* __restrict__ bucket_base,
        int* __restrict__ rowptr, int* __restrict__ deg, int* __restrict__ col,
        int N, int E, int half) {
    __shared__ int ldeg[512];
    __shared__ int ldeg_lo[512];
    __shared__ int buf[512];
    __shared__ int lcur_lo[512];
    __shared__ int lcur_hi[512];
    const int b = blockIdx.x, tid = threadIdx.x;
    const int segbase = bucket_base[b];
    const int L = bucket_base[b + 1] - segbase;
    ldeg[tid] = 0; ldeg_lo[tid] = 0;
    __syncthreads();
    for (int i = tid; i < L; i += 512) {
        const unsigned p = ebuf[segbase + i];
        const int ln = p >> 17;
        atomicAdd(&ldeg[ln], 1);
        if ((int)(p & 0x1FFFFu) < half) atomicAdd(&ldeg_lo[ln], 1);
    }
    __syncthreads();
    buf[tid] = ldeg[tid];
    __syncthreads();
    for (int off = 1; off < 512; off <<= 1) {
        const int t = (tid >= off) ? buf[tid - off] : 0;
        __syncthreads();
        buf[tid] += t;
        __syncthreads();
    }
    const int excl = buf[tid] - ldeg[tid];
    const int node = (b << 9) + tid;
    if (node < N) { rowptr[node] = segbase + excl; deg[node] = ldeg[tid]; }
    lcur_lo[tid] = excl;
    lcur_hi[tid] = excl + ldeg_lo[tid];
    __syncthreads();
    for (int i = tid; i < L; i += 512) {
        const unsigned p = ebuf[segbase + i];
        const int ln = p >> 17;
        const int s  = (int)(p & 0x1FFFFu);
        int pos = (s < half) ? atomicAdd(&lcur_lo[ln], 1) : atomicAdd(&lcur_hi[ln], 1);
        pos = min(segbase + pos, E - 1);             // defensive
        col[pos] = s;
    }
}

// ---------------- MFMA transform: y_l = A@Wl (fp8|bf16), y_r = A@Wr+b (bf16) -
template <int K, int F_OUT, int PAD, bool AFP32, bool YL8>
__global__ __launch_bounds__(256) void transform_kernel(
        const void* __restrict__ Ain, const float* __restrict__ Wl,
        const float* __restrict__ Wr, const float* __restrict__ b,
        void* __restrict__ yl, unsigned short* __restrict__ yr, int n) {
    constexpr int KSTEP = K / 32;
    constexpr int NT = PAD / 16;
    const int lane = threadIdx.x & 63;
    const int wid = (blockIdx.x * blockDim.x + threadIdx.x) >> 6;
    const int ntiles = (n + 15) >> 4;
    if (wid >= ntiles) return;
    const int nl = lane & 15, q = lane >> 4;

    short8 Bl[NT][KSTEP], Br[NT][KSTEP];
    float biasv[NT];
#pragma unroll
    for (int t = 0; t < NT; ++t) {
        const int ncol = t * 16 + nl;
        biasv[t] = (ncol < F_OUT) ? b[ncol] : 0.f;
#pragma unroll
        for (int ks = 0; ks < KSTEP; ++ks) {
#pragma unroll
            for (int j = 0; j < 8; ++j) {
                const int k = ks * 32 + q * 8 + j;
                Bl[t][ks][j] = (ncol < F_OUT) ? (short)f2bf(Wl[k * F_OUT + ncol]) : (short)0;
                Br[t][ks][j] = (ncol < F_OUT) ? (short)f2bf(Wr[k * F_OUT + ncol]) : (short)0;
            }
        }
    }

    const int m0 = wid * 16;
    int m = m0 + nl; if (m >= n) m = n - 1;

    short8 a[KSTEP];
#pragma unroll
    for (int ks = 0; ks < KSTEP; ++ks) {
        if (AFP32) {
            const float* p = (const float*)Ain + (size_t)m * K + ks * 32 + q * 8;
#pragma unroll
            for (int j = 0; j < 8; ++j) a[ks][j] = (short)f2bf(p[j]);
        } else {
            union { uint4 u; short8 s; } cvt;
            cvt.u = *(const uint4*)((const unsigned short*)Ain + (size_t)m * K + ks * 32 + q * 8);
            a[ks] = cvt.s;
        }
    }

    floatx4 accl[NT], accr[NT];
#pragma unroll
    for (int t = 0; t < NT; ++t) { accl[t] = {0.f,0.f,0.f,0.f}; accr[t] = {0.f,0.f,0.f,0.f}; }
#pragma unroll
    for (int ks = 0; ks < KSTEP; ++ks) {
#pragma unroll
        for (int t = 0; t < NT; ++t) {
            accl[t] = __builtin_amdgcn_mfma_f32_16x16x32_bf16(a[ks], Bl[t][ks], accl[t], 0, 0, 0);
            accr[t] = __builtin_amdgcn_mfma_f32_16x16x32_bf16(a[ks], Br[t][ks], accr[t], 0, 0, 0);
        }
    }

#pragma unroll
    for (int t = 0; t < NT; ++t) {
        const int ncol = t * 16 + nl;
#pragma unroll
        for (int r = 0; r < 4; ++r) {
            const int node = m0 + q * 4 + r;
            if (node < n) {
                if (YL8)
                    ((unsigned char*)yl)[(size_t)node * PAD + ncol] = f2fp8(accl[t][r]);
                else
                    ((unsigned short*)yl)[(size_t)node * PAD + ncol] = f2bf(accl[t][r]);
                yr[(size_t)node * PAD + ncol] = f2bf(accr[t][r] + biasv[t]);
            }
        }
    }
}

// ---------------- aggregate: h = act(norm(mean_gather(yl) + yr)) ------------
// PK: 0 = bf16 payload (uint4/row-chunk), 1 = fp8 payload (uint2/row-chunk).
template <int F, int ACT, int PK>
__global__ __launch_bounds__(256) void agg_kernel(
        const void* __restrict__ yl, const unsigned short* __restrict__ yr,
        const int* __restrict__ rowptr, const int* __restrict__ degv,
        const int* __restrict__ col,
        unsigned short* __restrict__ hout, float* __restrict__ fout, int n) {
    constexpr int G = F / 8;
    constexpr int NPW = 64 / G;
    const int lane = threadIdx.x & 63;
    const int wid = (blockIdx.x * blockDim.x + threadIdx.x) >> 6;
    const int g = lane / G, c = lane % G;
    const int node = wid * NPW + g;
    if (node >= n) return;

    const int beg = rowptr[node];
    const int dg  = degv[node];
    const int nmax = n - 1;

    float a0=0.f,a1=0.f,a2=0.f,a3=0.f,a4=0.f,a5=0.f,a6=0.f,a7=0.f;
    int i = 0;
    if (PK == 1) {
        const unsigned char* base = (const unsigned char*)yl + c * 8;
        auto accrow = [&](uint2 t) {
            const floatx2 p0 = __builtin_amdgcn_cvt_pk_f32_fp8((int)t.x, false);
            const floatx2 p1 = __builtin_amdgcn_cvt_pk_f32_fp8((int)t.x, true);
            const floatx2 p2 = __builtin_amdgcn_cvt_pk_f32_fp8((int)t.y, false);
            const floatx2 p3 = __builtin_amdgcn_cvt_pk_f32_fp8((int)t.y, true);
            a0 += p0.x; a1 += p0.y; a2 += p1.x; a3 += p1.y;
            a4 += p2.x; a5 += p2.y; a6 += p3.x; a7 += p3.y;
        };
        for (; i + 4 <= dg; i += 4) {
            const int n0 = min(col[beg + i],     nmax);
            const int n1 = min(col[beg + i + 1], nmax);
            const int n2 = min(col[beg + i + 2], nmax);
            const int n3 = min(col[beg + i + 3], nmax);
            const uint2 t0 = *(const uint2*)(base + (size_t)n0 * F);
            const uint2 t1 = *(const uint2*)(base + (size_t)n1 * F);
            const uint2 t2 = *(const uint2*)(base + (size_t)n2 * F);
            const uint2 t3 = *(const uint2*)(base + (size_t)n3 * F);
            accrow(t0); accrow(t1); accrow(t2); accrow(t3);
        }
        for (; i < dg; ++i) {
            const int n0 = min(col[beg + i], nmax);
            accrow(*(const uint2*)(base + (size_t)n0 * F));
        }
    } else {
        const unsigned short* base = (const unsigned short*)yl + c * 8;
        for (; i + 4 <= dg; i += 4) {
            const int n0 = min(col[beg + i],     nmax);
            const int n1 = min(col[beg + i + 1], nmax);
            const int n2 = min(col[beg + i + 2], nmax);
            const int n3 = min(col[beg + i + 3], nmax);
            const uint4 t0 = *(const uint4*)(base + (size_t)n0 * F);
            const uint4 t1 = *(const uint4*)(base + (size_t)n1 * F);
            const uint4 t2 = *(const uint4*)(base + (size_t)n2 * F);
            const uint4 t3 = *(const uint4*)(base + (size_t)n3 * F);
            a0 += blo(t0.x) + blo(t1.x) + blo(t2.x) + blo(t3.x);
            a1 += bhi(t0.x) + bhi(t1.x) + bhi(t2.x) + bhi(t3.x);
            a2 += blo(t0.y) + blo(t1.y) + blo(t2.y) + blo(t3.y);
            a3 += bhi(t0.y) + bhi(t1.y) + bhi(t2.y) + bhi(t3.y);
            a4 += blo(t0.z) + blo(t1.z) + blo(t2.z) + blo(t3.z);
            a5 += bhi(t0.z) + bhi(t1.z) + bhi(t2.z) + bhi(t3.z);
            a6 += blo(t0.w) + blo(t1.w) + blo(t2.w) + blo(t3.w);
            a7 += bhi(t0.w) + bhi(t1.w) + bhi(t2.w) + bhi(t3.w);
        }
        for (; i < dg; ++i) {
            const int n0 = min(col[beg + i], nmax);
            const uint4 t0 = *(const uint4*)(base + (size_t)n0 * F);
            a0 += blo(t0.x); a1 += bhi(t0.x); a2 += blo(t0.y); a3 += bhi(t0.y);
            a4 += blo(t0.z); a5 += bhi(t0.z); a6 += blo(t0.w); a7 += bhi(t0.w);
        }
    }
    const float inv = (dg > 0) ? 1.f / (float)dg : 0.f;

    // yr residual: bf16, coalesced
    const uint4 rv = *(const uint4*)(yr + (size_t)node * F + c * 8);
    float o[8];
    o[0] = a0*inv + blo(rv.x); o[1] = a1*inv + bhi(rv.x);
    o[2] = a2*inv + blo(rv.y); o[3] = a3*inv + bhi(rv.y);
    o[4] = a4*inv + blo(rv.z); o[5] = a5*inv + bhi(rv.z);
    o[6] = a6*inv + blo(rv.w); o[7] = a7*inv + bhi(rv.w);

    float ss = 0.f;
#pragma unroll
    for (int j = 0; j < 8; ++j) ss += o[j] * o[j];
#pragma unroll
    for (int off = 1; off < G; off <<= 1) ss += __shfl_xor(ss, off);
    const float scale = 1.f / fmaxf(sqrtf(ss), 1e-12f);

    if (ACT == 1) {
        uint4 u;
        float h[8];
#pragma unroll
        for (int j = 0; j < 8; ++j) h[j] = fmaxf(o[j] * scale, 0.f);
        u.x = (unsigned)f2bf(h[0]) | ((unsigned)f2bf(h[1]) << 16);
        u.y = (unsigned)f2bf(h[2]) | ((unsigned)f2bf(h[3]) << 16);
        u.z = (unsigned)f2bf(h[4]) | ((unsigned)f2bf(h[5]) << 16);
        u.w = (unsigned)f2bf(h[6]) | ((unsigned)f2bf(h[7]) << 16);
        *(uint4*)(hout + (size_t)node * F + c * 8) = u;
    } else {
#pragma unroll
        for (int j = 0; j < 8; ++j) o[j] *= scale;
        const int cbase = c * 8;
        float m = -INFINITY;
#pragma unroll
        for (int j = 0; j < 8; ++j) if (cbase + j < 10) m = fmaxf(m, o[j]);
        m = fmaxf(m, __shfl_xor(m, 1));
        float s = 0.f;
#pragma unroll
        for (int j = 0; j < 8; ++j) if (cbase + j < 10) s += __expf(o[j] - m);
        s += __shfl_xor(s, 1);
        const float ls = logf(s);
#pragma unroll
        for (int j = 0; j < 8; ++j)
            if (cbase + j < 10) fout[(size_t)node * 10 + cbase + j] = o[j] - m - ls;
    }
}

extern "C" void kernel_launch(void* const* d_in, const int* in_sizes, int n_in,
                              void* d_out, int out_size, void* d_ws, size_t ws_size,
                              hipStream_t stream) {
    const float* x   = (const float*)d_in[0];
    const int*   ei  = (const int*)d_in[1];     // int64 in ref -> int32 on device
    const float* W1l = (const float*)d_in[2];
    const float* W1r = (const float*)d_in[3];
    const float* b1  = (const float*)d_in[4];
    const float* W2l = (const float*)d_in[5];
    const float* W2r = (const float*)d_in[6];
    const float* b2  = (const float*)d_in[7];
    const float* W3l = (const float*)d_in[8];
    const float* W3r = (const float*)d_in[9];
    const float* b3  = (const float*)d_in[10];
    float*       out = (float*)d_out;

    const int N = in_sizes[0] / 64;
    const int E = in_sizes[1] / 2;
    const int NBKT = (N + 511) >> 9;     // dst buckets of 512 nodes (<=256)
    const int NB   = (E + 4095) >> 12;   // 4096 edges per hist/scatter block

    auto align16 = [](size_t v) { return (v + 15) & ~(size_t)15; };
    char* ws = (char*)d_ws;
    size_t off = 0;
    int* rowptr  = (int*)(ws + off); off = align16(off + (size_t)N * 4);
    int* deg     = (int*)(ws + off); off = align16(off + (size_t)N * 4);
    int* colidx  = (int*)(ws + off); off = align16(off + (size_t)E * 4);
    unsigned* ebuf = (unsigned*)(ws + off); off = align16(off + (size_t)E * 4);
    int* bh      = (int*)(ws + off); off = align16(off + (size_t)NBKT * NB * 4);
    int* offsb   = (int*)(ws + off); off = align16(off + (size_t)NBKT * NB * 4);
    int* btot    = (int*)(ws + off); off = align16(off + (size_t)NBKT * 4);
    int* bbase   = (int*)(ws + off); off = align16(off + (size_t)(NBKT + 1) * 4);
    unsigned char*  y1l = (unsigned char*)(ws + off);  off = align16(off + (size_t)N * 64);
    unsigned short* y1r = (unsigned short*)(ws + off); off = align16(off + (size_t)N * 64 * 2);
    unsigned short* h1  = (unsigned short*)(ws + off); off = align16(off + (size_t)N * 64 * 2);
    unsigned char*  y2l = (unsigned char*)(ws + off);  off = align16(off + (size_t)N * 32);
    unsigned short* y2r = (unsigned short*)(ws + off); off = align16(off + (size_t)N * 32 * 2);
    unsigned short* h2  = (unsigned short*)(ws + off); off = align16(off + (size_t)N * 32 * 2);
    unsigned short* y3l = (unsigned short*)(ws + off); off = align16(off + (size_t)N * 16 * 2);
    unsigned short* y3r = (unsigned short*)(ws + off); off = align16(off + (size_t)N * 16 * 2);
    (void)ws_size; (void)n_in; (void)out_size;

    // ---- CSR build (atomic-free bucket sort, src-half-ordered rows)
    hist_kernel<<<NB, 256, 0, stream>>>(ei, bh, E, NB, NBKT);
    bscan_kernel<<<(NBKT + 3) / 4, 256, 0, stream>>>(bh, offsb, btot, NB, NBKT);
    bucketbase_kernel<<<1, 64, 0, stream>>>(btot, bbase, NBKT);
    scatter_kernel<<<NB, 256, 0, stream>>>(ei, offsb, bbase, ebuf, E, NB, NBKT);
    bucket_csr_kernel<<<NBKT, 512, 0, stream>>>(ebuf, bbase, rowptr, deg, colidx, N, E, N / 2);

    const int ntiles = (N + 15) / 16;                  // MFMA node tiles
    const int tblocks = (ntiles * 64 + 255) / 256;     // 4 waves/block

    // layer 1 (fp8 gather payload)
    transform_kernel<64, 64, 64, true, true><<<tblocks, 256, 0, stream>>>(
        x, W1l, W1r, b1, y1l, y1r, N);
    agg_kernel<64, 1, 1><<<(N + 31) / 32, 256, 0, stream>>>(
        y1l, y1r, rowptr, deg, colidx, h1, nullptr, N);
    // layer 2 (fp8 gather payload)
    transform_kernel<64, 32, 32, false, true><<<tblocks, 256, 0, stream>>>(
        h1, W2l, W2r, b2, y2l, y2r, N);
    agg_kernel<32, 1, 1><<<(N + 63) / 64, 256, 0, stream>>>(
        y2l, y2r, rowptr, deg, colidx, h2, nullptr, N);
    // layer 3 (bf16 payload, L2-resident)
    transform_kernel<32, 10, 16, false, false><<<tblocks, 256, 0, stream>>>(
        h2, W3l, W3r, b3, y3l, y3r, N);
    agg_kernel<16, 2, 0><<<(N + 127) / 128, 256, 0, stream>>>(
        y3l, y3r, rowptr, deg, colidx, nullptr, out, N);
}